// Round 15
// baseline (1334.183 us; speedup 1.0000x reference)
//
#include <hip/hip_runtime.h>
#include <hip/hip_bf16.h>

// ============================================================================
// seq2seq + attention on MI355X.  B=32, Te=64, Td=32 (31 steps), E=256, H=512,
// V=32000.  Round 15: fix round-14's race — WT (wdf transpose output) aliased
// XB while mega_enc's folded transpose workers wrote it CONCURRENTLY with the
// backward-direction encoder reading XB.  WT now has a dedicated allocation.
// Design otherwise identical to round 14:
//   - wout->bf16 conversion folded into mega_dec (64 extra blocks, grid 224)
//   - wdf transpose folded into mega_enc (160 extra blocks, grid 224)
//   - mega_enc: 32 blocks/dir x 16 units; mega_dec: round-11 structure
//   - bf16 logits GEMM (ws-guarded), 128x128 XCD-swizzled
// ============================================================================

typedef __attribute__((ext_vector_type(8))) short bfrag_t;
typedef __attribute__((ext_vector_type(4))) float f4_t;

static __device__ __forceinline__ float bf2f(unsigned short u) {
  union { float f; unsigned int i; } v; v.i = ((unsigned int)u) << 16; return v.f;
}
static __device__ __forceinline__ unsigned short f2bf(float f) {
  union { float f; unsigned int i; } v; v.f = f;
  unsigned int r = v.i + 0x7FFFu + ((v.i >> 16) & 1u);  // RNE
  return (unsigned short)(r >> 16);
}
static __device__ __forceinline__ unsigned int pack_bf2(float lo, float hi) {
  __hip_bfloat162 h2 = __float22bfloat162_rn(make_float2(lo, hi));
  union { __hip_bfloat162 h; unsigned int u; } cv; cv.h = h2;
  return cv.u;
}
static __device__ __forceinline__ float sigm(float x) {
  return __builtin_amdgcn_rcpf(1.f + __expf(-x));
}
static __device__ __forceinline__ float ftanh(float x) {
  float e = __expf(2.f * x);
  return 1.f - 2.f * __builtin_amdgcn_rcpf(e + 1.f);
}

#define GLDS16(g, l)                                                        \
  __builtin_amdgcn_global_load_lds(                                         \
      (const __attribute__((address_space(1))) void*)(g),                   \
      (__attribute__((address_space(3))) void*)(l), 16, 0, 0)

// ---- device-coherent (agent-scope) access helpers: bypass L2 via sc0 sc1 ----
static __device__ __forceinline__ void st_f32_coh(float* p, float v) {
  asm volatile("global_store_dword %0, %1, off sc0 sc1" :: "v"(p), "v"(v) : "memory");
}
static __device__ __forceinline__ void st_u16_coh(unsigned short* p, unsigned short x) {
  asm volatile("global_store_short %0, %1, off sc0 sc1" :: "v"(p), "v"((unsigned)x) : "memory");
}
static __device__ __forceinline__ float ld_f32_coh(const float* p) {
  float v;
  asm volatile("global_load_dword %0, %1, off sc0 sc1\n\ts_waitcnt vmcnt(0)"
               : "=v"(v) : "v"(p) : "memory");
  return v;
}

// ---------------------------------------------------------------------------
// Decoupled fence-free barrier primitives.
// ---------------------------------------------------------------------------
static __device__ __forceinline__ void arrive8(unsigned* base) {
  __syncthreads();
  if (threadIdx.x == 0)
    __hip_atomic_fetch_add(base + (blockIdx.x & 7) * 32, 1u,
                           __ATOMIC_RELAXED, __HIP_MEMORY_SCOPE_AGENT);
}
static __device__ __forceinline__ void wait8(unsigned* base, unsigned target) {
  if (threadIdx.x < 64) {
    unsigned sum;
    do {
      unsigned v = 0;
      if (threadIdx.x < 8)
        v = __hip_atomic_load(base + threadIdx.x * 32,
                              __ATOMIC_RELAXED, __HIP_MEMORY_SCOPE_AGENT);
      v += __shfl_xor(v, 1);
      v += __shfl_xor(v, 2);
      v += __shfl_xor(v, 4);
      sum = __shfl(v, 0);
      if (sum < target) __builtin_amdgcn_s_sleep(2);
    } while (sum < target);
  }
  __syncthreads();
}
static __device__ __forceinline__ void gbar8(unsigned* base, unsigned target) {
  arrive8(base);
  wait8(base, target);
}

// ---------------------------------------------------------------------------
// C = A(bf16, MxK, lda) @ B(fp32 NxldB rows, +bcol0)^T + bias.  128x128 tile.
// ---------------------------------------------------------------------------
__global__ __launch_bounds__(256) void gemm_bt_kernel(
    const unsigned short* __restrict__ A, int lda,
    const float* __restrict__ B, int ldb, int bcol0,
    const float* __restrict__ bias, void* __restrict__ Cv, int ldc,
    int Mvalid, int K, int Mt, int swz, int obf) {
  __shared__ unsigned short As[128 * 32];
  __shared__ unsigned short Bs[128 * 32];
  int id = blockIdx.x;
  if (swz) { int x = id & 7; id = x * ((int)gridDim.x >> 3) + (id >> 3); }
  const int mb = id % Mt, nb = id / Mt;
  const int m0 = mb * 128, n0 = nb * 128;
  const int tid = threadIdx.x;
  const int w = tid >> 6, lane = tid & 63;
  const int wr = (w >> 1) * 64, wc = (w & 1) * 64;
  const int l15 = lane & 15, l4 = lane >> 4;

  const int arow = w * 16 + (lane >> 2);
  const int acol = (lane & 3) * 8;
  const unsigned short* Ag = A + (size_t)(m0 + arow) * lda + acol;

  const int brow = tid >> 1;
  const int bcol = (tid & 1) * 16;
  const float* Bg = B + (size_t)(n0 + brow) * ldb + bcol0 + bcol;
  unsigned short* Bsw = Bs + brow * 32 + bcol;

  f4_t acc[4][4];
#pragma unroll
  for (int i = 0; i < 4; ++i)
#pragma unroll
    for (int j = 0; j < 4; ++j) {
      acc[i][j].x = 0.f; acc[i][j].y = 0.f; acc[i][j].z = 0.f; acc[i][j].w = 0.f;
    }

  for (int kt = 0; kt < K; kt += 32) {
    GLDS16(Ag + kt, As + w * 512);
    GLDS16(Ag + (size_t)64 * lda + kt, As + (4 + w) * 512);
    float4 q0 = *(const float4*)(Bg + kt);
    float4 q1 = *(const float4*)(Bg + kt + 4);
    float4 q2 = *(const float4*)(Bg + kt + 8);
    float4 q3 = *(const float4*)(Bg + kt + 12);
    union { unsigned int u[8]; uint4 q[2]; } pk;
    pk.u[0] = pack_bf2(q0.x, q0.y); pk.u[1] = pack_bf2(q0.z, q0.w);
    pk.u[2] = pack_bf2(q1.x, q1.y); pk.u[3] = pack_bf2(q1.z, q1.w);
    pk.u[4] = pack_bf2(q2.x, q2.y); pk.u[5] = pack_bf2(q2.z, q2.w);
    pk.u[6] = pack_bf2(q3.x, q3.y); pk.u[7] = pack_bf2(q3.z, q3.w);
    *(uint4*)(Bsw) = pk.q[0];
    *(uint4*)(Bsw + 8) = pk.q[1];
    __syncthreads();
    bfrag_t af[4], bfv[4];
#pragma unroll
    for (int m = 0; m < 4; ++m)
      af[m] = *(const bfrag_t*)(As + (wr + m * 16 + l15) * 32 + l4 * 8);
#pragma unroll
    for (int n = 0; n < 4; ++n)
      bfv[n] = *(const bfrag_t*)(Bs + (wc + n * 16 + l15) * 32 + l4 * 8);
#pragma unroll
    for (int m = 0; m < 4; ++m)
#pragma unroll
      for (int n = 0; n < 4; ++n)
        acc[m][n] = __builtin_amdgcn_mfma_f32_16x16x32_bf16(af[m], bfv[n], acc[m][n], 0, 0, 0);
    __syncthreads();
  }

  const int crb = l4 * 4;
  float* Cf = (float*)Cv;
  unsigned short* Ch = (unsigned short*)Cv;
#pragma unroll
  for (int m = 0; m < 4; ++m)
#pragma unroll
    for (int n = 0; n < 4; ++n)
#pragma unroll
      for (int r = 0; r < 4; ++r) {
        int gr = m0 + wr + m * 16 + crb + r;
        if (gr < Mvalid) {
          int gc = n0 + wc + n * 16 + l15;
          float v = acc[m][n][r] + (bias ? bias[gc] : 0.f);
          if (obf) Ch[(size_t)gr * ldc + gc] = f2bf(v);
          else     Cf[(size_t)gr * ldc + gc] = v;
        }
      }
}

// ---------------------------------------------------------------------------
// bf16 x bf16 variant: C = A @ B^T + bias; both staged via global_load_lds.
// ---------------------------------------------------------------------------
__global__ __launch_bounds__(256) void gemm_bt16_kernel(
    const unsigned short* __restrict__ A, int lda,
    const unsigned short* __restrict__ B, int ldb,
    const float* __restrict__ bias, float* __restrict__ C, int ldc,
    int Mvalid, int K, int Mt, int swz) {
  __shared__ unsigned short As[128 * 32];
  __shared__ unsigned short Bs[128 * 32];
  int id = blockIdx.x;
  if (swz) { int x = id & 7; id = x * ((int)gridDim.x >> 3) + (id >> 3); }
  const int mb = id % Mt, nb = id / Mt;
  const int m0 = mb * 128, n0 = nb * 128;
  const int tid = threadIdx.x;
  const int w = tid >> 6, lane = tid & 63;
  const int wr = (w >> 1) * 64, wc = (w & 1) * 64;
  const int l15 = lane & 15, l4 = lane >> 4;

  const int arow = w * 16 + (lane >> 2);
  const int acol = (lane & 3) * 8;
  const unsigned short* Ag = A + (size_t)(m0 + arow) * lda + acol;
  const unsigned short* Bg = B + (size_t)(n0 + arow) * ldb + acol;

  f4_t acc[4][4];
#pragma unroll
  for (int i = 0; i < 4; ++i)
#pragma unroll
    for (int j = 0; j < 4; ++j) {
      acc[i][j].x = 0.f; acc[i][j].y = 0.f; acc[i][j].z = 0.f; acc[i][j].w = 0.f;
    }

  for (int kt = 0; kt < K; kt += 32) {
    GLDS16(Ag + kt, As + w * 512);
    GLDS16(Ag + (size_t)64 * lda + kt, As + (4 + w) * 512);
    GLDS16(Bg + kt, Bs + w * 512);
    GLDS16(Bg + (size_t)64 * ldb + kt, Bs + (4 + w) * 512);
    __syncthreads();
    bfrag_t af[4], bfv[4];
#pragma unroll
    for (int m = 0; m < 4; ++m)
      af[m] = *(const bfrag_t*)(As + (wr + m * 16 + l15) * 32 + l4 * 8);
#pragma unroll
    for (int n = 0; n < 4; ++n)
      bfv[n] = *(const bfrag_t*)(Bs + (wc + n * 16 + l15) * 32 + l4 * 8);
#pragma unroll
    for (int m = 0; m < 4; ++m)
#pragma unroll
      for (int n = 0; n < 4; ++n)
        acc[m][n] = __builtin_amdgcn_mfma_f32_16x16x32_bf16(af[m], bfv[n], acc[m][n], 0, 0, 0);
    __syncthreads();
  }

  const int crb = l4 * 4;
#pragma unroll
  for (int m = 0; m < 4; ++m)
#pragma unroll
    for (int n = 0; n < 4; ++n)
#pragma unroll
      for (int r = 0; r < 4; ++r) {
        int gr = m0 + wr + m * 16 + crb + r;
        if (gr < Mvalid) {
          int gc = n0 + wc + n * 16 + l15;
          C[(size_t)gr * ldc + gc] = acc[m][n][r] + bias[gc];
        }
      }
}

// ---------------------------------------------------------------------------
// Embedding gathers -> bf16   (unchanged)
// ---------------------------------------------------------------------------
__global__ void gather_enc_kernel(const int* __restrict__ texts,
                                  const float* __restrict__ table,
                                  unsigned short* __restrict__ out) {
  const int row = blockIdx.x;
  const int tok = texts[row];
  const float4 v = *(const float4*)(table + (size_t)tok * 256 + threadIdx.x * 4);
  unsigned short* o = out + (size_t)row * 256 + threadIdx.x * 4;
  o[0] = f2bf(v.x); o[1] = f2bf(v.y); o[2] = f2bf(v.z); o[3] = f2bf(v.w);
}

__global__ void gather_dec_kernel(const int* __restrict__ texts,
                                  const float* __restrict__ table,
                                  unsigned short* __restrict__ out) {
  const int row = blockIdx.x;
  unsigned short* o = out + (size_t)row * 256 + threadIdx.x * 4;
  if (row >= 992) { o[0] = 0; o[1] = 0; o[2] = 0; o[3] = 0; return; }
  const int b = row / 31, t2 = row - b * 31;
  const int tok = texts[b * 32 + t2];
  const float4 v = *(const float4*)(table + (size_t)tok * 256 + threadIdx.x * 4);
  o[0] = f2bf(v.x); o[1] = f2bf(v.y); o[2] = f2bf(v.z); o[3] = f2bf(v.w);
}

// ---------------------------------------------------------------------------
// Encoder megakernel (MFMA) + folded W_df transpose workers.
// Grid 224: blocks 0..63 = encoder (32/dir x 16 units); 64..223 = wdf workers.
// WT has a DEDICATED allocation (must not alias XF/XB: concurrent!).
// ---------------------------------------------------------------------------
__global__ __launch_bounds__(256) void mega_enc_kernel(
    const float* __restrict__ XF, const float* __restrict__ XB,
    const float* __restrict__ Whh_f, const float* __restrict__ Whh_b,
    const float* __restrict__ mask,
    unsigned short* __restrict__ HBF,   // [dir][pp][32*512] bf16
    unsigned short* __restrict__ ENCO, float* __restrict__ HFIN,
    const float* __restrict__ W_df, const float* __restrict__ b_df,
    float* __restrict__ WT, unsigned* bar) {
  const int bi = blockIdx.x;
  const int tid = threadIdx.x;

  __shared__ union {
    struct {
      unsigned short WA[64 * 520];   // 64 gate-rows: (gate*16+ul)
      unsigned short HB[32 * 520];   // row = batch
      float Gl[64][33];
    } e;
    struct { float tl[32][33]; } tr;
  } S;

  if (bi >= 64) {
    // ---- W_df transpose workers: jobs 0..1024 over 160 blocks ----
    for (int job = bi - 64; job < 1025; job += 160) {
      if (job < 1024) {
        const int tx = (job & 31) * 32, ty = (job >> 5) * 32;
        const int r = tid >> 5, c = tid & 31;
#pragma unroll
        for (int i = 0; i < 4; ++i)
          S.tr.tl[r + i * 8][c] = W_df[(size_t)(ty + r + i * 8) * 1024 + tx + c];
        __syncthreads();
#pragma unroll
        for (int i = 0; i < 4; ++i)
          WT[(size_t)(tx + r + i * 8) * 1024 + ty + c] = S.tr.tl[c][r + i * 8];
        __syncthreads();
      } else {
        for (int i = tid; i < 1024; i += 256)
          WT[(size_t)1024 * 1024 + i] = b_df[i];
      }
    }
    return;
  }

  const int dir = bi >> 5;
  const int u0 = (bi & 31) * 16;
  const float* X = dir ? XB : XF;
  const float* W = dir ? Whh_b : Whh_f;
  unsigned short* Hbf = HBF + dir * 32768;
  unsigned* cnt = bar + dir * 256;    // 1 KiB group per direction

  // preload W: row r (0..63) -> Whh[(r>>4)*512 + u0 + (r&15)], bf16
#pragma unroll
  for (int i = 0; i < 32; ++i) {
    int idx = tid + i * 256;          // 64 rows x 128 float4-cols
    int r = idx >> 7, c4 = idx & 127;
    const float4 v = *(const float4*)(W + (size_t)((r >> 4) * 512 + u0 + (r & 15)) * 512 + c4 * 4);
    *(uint2*)(S.e.WA + r * 520 + c4 * 4) = make_uint2(pack_bf2(v.x, v.y), pack_bf2(v.z, v.w));
  }
  __syncthreads();

  const int w = tid >> 6, lane = tid & 63;
  const int l15 = lane & 15, l4 = lane >> 4;
  const int wrow = w * 16;            // wave's 16 gate-rows

  bfrag_t afr[16];
#pragma unroll
  for (int kk = 0; kk < 16; ++kk)
    afr[kk] = *(const bfrag_t*)(S.e.WA + (wrow + l15) * 520 + kk * 32 + l4 * 8);

  const int ob = tid & 31, ouo = tid >> 5;   // batch, unit offset (0..7; pairs +8)
  float h_reg0 = 0.f, c_reg0 = 0.f, h_reg1 = 0.f, c_reg1 = 0.f;

  unsigned tgt = 0;
  for (int s = 0; s < 64; ++s) {
    const int t = dir ? (63 - s) : s;
    const int pp = s & 1;
    const float* xp = X + ((size_t)ob * 64 + t) * 2048 + u0;
    float xg[2][4];
#pragma unroll
    for (int p = 0; p < 2; ++p) {
      int ul = ouo + p * 8;
      xg[p][0] = xp[ul]; xg[p][1] = xp[512 + ul];
      xg[p][2] = xp[1024 + ul]; xg[p][3] = xp[1536 + ul];
    }
    float mval = mask[ob * 64 + t];
    // stage h (bf16, 32 rows x 64 uint4/row) via coherent loads
    const unsigned short* hsrc = Hbf + pp * 16384;
    uint4 tmp[8];
#pragma unroll
    for (int i = 0; i < 8; ++i) {
      int idx = tid + i * 256;
      int r = idx >> 6, c = idx & 63;
      asm volatile("global_load_dwordx4 %0, %1, off sc0 sc1"
                   : "=v"(tmp[i]) : "v"(hsrc + r * 512 + c * 8));
    }
    asm volatile("s_waitcnt vmcnt(0)" ::: "memory");
#pragma unroll
    for (int i = 0; i < 8; ++i) {
      int idx = tid + i * 256;
      int r = idx >> 6, c = idx & 63;
      *(uint4*)(S.e.HB + r * 520 + c * 8) = tmp[i];
    }
    __syncthreads();
    {
      f4_t a0 = {0.f, 0.f, 0.f, 0.f}, a1 = {0.f, 0.f, 0.f, 0.f};
#pragma unroll
      for (int kk = 0; kk < 16; ++kk) {
        bfrag_t b0 = *(const bfrag_t*)(S.e.HB + l15 * 520 + kk * 32 + l4 * 8);
        bfrag_t b1 = *(const bfrag_t*)(S.e.HB + (16 + l15) * 520 + kk * 32 + l4 * 8);
        a0 = __builtin_amdgcn_mfma_f32_16x16x32_bf16(afr[kk], b0, a0, 0, 0, 0);
        a1 = __builtin_amdgcn_mfma_f32_16x16x32_bf16(afr[kk], b1, a1, 0, 0, 0);
      }
#pragma unroll
      for (int r = 0; r < 4; ++r) {
        S.e.Gl[wrow + l4 * 4 + r][l15] = a0[r];
        S.e.Gl[wrow + l4 * 4 + r][16 + l15] = a1[r];
      }
    }
    __syncthreads();
#pragma unroll
    for (int p = 0; p < 2; ++p) {
      const int ul = ouo + p * 8;
      const int ou = u0 + ul;
      float& h_reg = p ? h_reg1 : h_reg0;
      float& c_reg = p ? c_reg1 : c_reg0;
      float gi = S.e.Gl[ul][ob] + xg[p][0];
      float gf = S.e.Gl[16 + ul][ob] + xg[p][1];
      float gg = S.e.Gl[32 + ul][ob] + xg[p][2];
      float go = S.e.Gl[48 + ul][ob] + xg[p][3];
      float cn = sigm(gf) * c_reg + sigm(gi) * ftanh(gg);
      float hn = sigm(go) * ftanh(cn);
      float hmix = mval * hn + (1.f - mval) * h_reg;
      float cmix = mval * cn + (1.f - mval) * c_reg;
      h_reg = hmix; c_reg = cmix;
      ENCO[((size_t)ob * 64 + t) * 1024 + dir * 512 + ou] = f2bf(hmix * mval);
      st_u16_coh(Hbf + (pp ^ 1) * 16384 + ob * 512 + ou, f2bf(hmix));
      if (s == 63) {
        HFIN[dir * 16384 + ob * 512 + ou] = hmix;
        HFIN[(2 + dir) * 16384 + ob * 512 + ou] = cmix;
      }
    }
    if (s < 63) { tgt += 32; gbar8(cnt, tgt); }
  }
}

// ---------------------------------------------------------------------------
// Decoder megakernel (MFMA) + folded W_out->bf16 converters.
// Grid 224: 0-127 gates, 128-159 attention, 160-223 converters.
// ---------------------------------------------------------------------------
__global__ __launch_bounds__(256) void mega_dec_kernel(
    const float* __restrict__ HFIN, const float* __restrict__ W_h,
    const float* __restrict__ b_h, const float* __restrict__ W_c,
    const float* __restrict__ b_c, const float* __restrict__ XD,
    const float* __restrict__ Wih_d, const float* __restrict__ Whh_d,
    const unsigned short* __restrict__ EFG, const unsigned short* __restrict__ ENCO,
    const float* __restrict__ mask, float* __restrict__ DECH,
    float* __restrict__ DECC, unsigned short* __restrict__ PRE0,
    unsigned short* __restrict__ ACAT,
    const float* __restrict__ W_out, unsigned short* __restrict__ WOB,
    int do_conv, unsigned* bar) {
  const int bi = blockIdx.x;
  const int tid = threadIdx.x;

  if (bi >= 160) {
    // ---- W_out fp32 -> bf16 converters (64 blocks, no barriers) ----
    if (do_conv) {
      const int cb = bi - 160;
      for (size_t base = (size_t)cb * 2048 + tid * 8;
           base < (size_t)32000 * 1536; base += (size_t)64 * 2048) {
        float4 a = *(const float4*)(W_out + base);
        float4 b = *(const float4*)(W_out + base + 4);
        uint4 o;
        o.x = pack_bf2(a.x, a.y); o.y = pack_bf2(a.z, a.w);
        o.z = pack_bf2(b.x, b.y); o.w = pack_bf2(b.z, b.w);
        *(uint4*)(WOB + base) = o;
      }
    }
    return;
  }

  const bool is_attn = (bi >= 128);
  const int u0 = bi * 4;            // gates blocks only
  unsigned* barB1 = bar;            // arrivals: gates (128/step + 128 init)
  unsigned* barB2 = bar + 256;      // arrivals: attn (32/step)

  __shared__ union {
    struct {
      unsigned short wga[16 * 1544];
      unsigned short xb[32 * 1544];
      float gl[16][33];
    } s;
    struct {
      unsigned short efg[64 * 1160];
      float hcl[1024];
      float scl[64];
      float al[64];
    } a;
    struct { float xl[32][132]; float wi[8][132]; } ini;
  } U;

  const int ob = tid & 31, ouo = (tid >> 5) & 3, ou = u0 + ouo;
  const int w = tid >> 6, lane = tid & 63;
  const int l15 = lane & 15, l4 = lane >> 4;

  if (!is_attn) {
    // ---- init: dec_h = relu([hf,hb]@W_h^T+b_h); dec_c likewise (fp32) ----
    {
      const int mat = bi >> 6, j0i = (bi & 63) * 8;
      const int jj = tid >> 5, b = tid & 31;
      const int sr = tid >> 5, sc = (tid & 31) * 4;
      const float* Wm = mat ? W_c : W_h;
      const float* bias = mat ? b_c : b_h;
      const float* x0 = HFIN + (size_t)(mat ? 2 : 0) * 16384;
      const float* x1 = HFIN + (size_t)(mat ? 3 : 1) * 16384;
      float acc = 0.f;
      for (int kc = 0; kc < 1024; kc += 128) {
#pragma unroll
        for (int i = 0; i < 4; ++i) {
          int r = sr + i * 8;
          const float* src = (kc < 512) ? (x0 + r * 512 + kc + sc)
                                        : (x1 + r * 512 + (kc - 512) + sc);
          *(float4*)&U.ini.xl[r][sc] = *(const float4*)src;
        }
        *(float4*)&U.ini.wi[sr][sc] = *(const float4*)(Wm + (size_t)(j0i + sr) * 1024 + kc + sc);
        __syncthreads();
#pragma unroll
        for (int k = 0; k < 128; k += 4) {
          float4 wv = *(const float4*)&U.ini.wi[jj][k];
          float4 xv = *(const float4*)&U.ini.xl[b][k];
          acc += wv.x * xv.x + wv.y * xv.y + wv.z * xv.z + wv.w * xv.w;
        }
        __syncthreads();
      }
      float v = fmaxf(acc + bias[j0i + jj], 0.f);
      if (mat == 0) {
        st_f32_coh(DECH + b * 512 + j0i + jj, v);
        st_u16_coh(PRE0 + (size_t)b * 1536 + j0i + jj, f2bf(v));
      } else {
        st_f32_coh(DECC + b * 512 + j0i + jj, v);
      }
    }
    arrive8(barB1);
    wait8(barB1, 128);

    // ---- preconvert gates A to bf16 LDS ----
#pragma unroll
    for (int i = 0; i < 24; ++i) {
      int idx = tid + i * 256;
      int r = idx / 384, c4 = idx - (idx / 384) * 384;
      int wrow = (r >> 2) * 512 + u0 + (r & 3);
      int c = c4 * 4;
      float4 v;
      if (c < 512) v = *(const float4*)(Whh_d + (size_t)wrow * 512 + c);
      else         v = *(const float4*)(Wih_d + (size_t)wrow * 1280 + 256 + (c - 512));
      *(uint2*)(U.s.wga + r * 1544 + c) = make_uint2(pack_bf2(v.x, v.y), pack_bf2(v.z, v.w));
    }
    float h_reg = 0.f, c_reg = 0.f;
    if (tid < 128) {
      h_reg = ld_f32_coh(DECH + ob * 512 + ou);
      c_reg = ld_f32_coh(DECC + ob * 512 + ou);
    }

    f4_t cae = {0.f, 0.f, 0.f, 0.f}, cao = {0.f, 0.f, 0.f, 0.f};  // carried

    for (int t = 0; t < 31; ++t) {
      float xg0 = 0, xg1 = 0, xg2 = 0, xg3 = 0;
      if (tid < 128) {
        const float* xp = XD + ((size_t)ob * 31 + t) * 2048 + ou;
        xg0 = xp[0]; xg1 = xp[512]; xg2 = xp[1024]; xg3 = xp[1536];
      }
      if (t == 0) {
        uint4 tmp[24];
#pragma unroll
        for (int i = 0; i < 24; ++i) {
          int idx = tid + i * 256;
          int r = idx / 192, c16 = idx - (idx / 192) * 192;
          asm volatile("global_load_dwordx4 %0, %1, off sc0 sc1"
                       : "=v"(tmp[i]) : "v"(PRE0 + (size_t)r * 1536 + c16 * 8));
        }
        asm volatile("s_waitcnt vmcnt(0)" ::: "memory");
#pragma unroll
        for (int i = 0; i < 24; ++i) {
          int idx = tid + i * 256;
          int r = idx / 192, c16 = idx - (idx / 192) * 192;
          *(uint4*)(U.s.xb + r * 1544 + c16 * 8) = tmp[i];
        }
        __syncthreads();
        if (w < 2) {
          f4_t ae = {0.f, 0.f, 0.f, 0.f}, ao = {0.f, 0.f, 0.f, 0.f};
#pragma unroll
          for (int kk = 0; kk < 48; kk += 2) {
            bfrag_t a0 = *(const bfrag_t*)(U.s.wga + l15 * 1544 + kk * 32 + l4 * 8);
            bfrag_t b0 = *(const bfrag_t*)(U.s.xb + (w * 16 + l15) * 1544 + kk * 32 + l4 * 8);
            bfrag_t a1 = *(const bfrag_t*)(U.s.wga + l15 * 1544 + (kk + 1) * 32 + l4 * 8);
            bfrag_t b1 = *(const bfrag_t*)(U.s.xb + (w * 16 + l15) * 1544 + (kk + 1) * 32 + l4 * 8);
            ae = __builtin_amdgcn_mfma_f32_16x16x32_bf16(a0, b0, ae, 0, 0, 0);
            ao = __builtin_amdgcn_mfma_f32_16x16x32_bf16(a1, b1, ao, 0, 0, 0);
          }
#pragma unroll
          for (int r = 0; r < 4; ++r)
            U.s.gl[l4 * 4 + r][w * 16 + l15] = ae[r] + ao[r];
        }
      } else {
        wait8(barB2, 32u * t);
        uint4 tmp[16];
#pragma unroll
        for (int i = 0; i < 16; ++i) {
          int idx = tid + i * 256;
          int r = idx >> 7, c16 = 64 + (idx & 127);
          asm volatile("global_load_dwordx4 %0, %1, off sc0 sc1"
                       : "=v"(tmp[i]) : "v"(ACAT + ((size_t)r * 31 + (t - 1)) * 1536 + c16 * 8));
        }
        asm volatile("s_waitcnt vmcnt(8)" ::: "memory");
#pragma unroll
        for (int i = 0; i < 8; ++i) {
          int idx = tid + i * 256;
          int r = idx >> 7, c16 = 64 + (idx & 127);
          *(uint4*)(U.s.xb + r * 1544 + c16 * 8) = tmp[i];
        }
        asm volatile("s_waitcnt vmcnt(0)" ::: "memory");
#pragma unroll
        for (int i = 8; i < 16; ++i) {
          int idx = tid + i * 256;
          int r = idx >> 7, c16 = 64 + (idx & 127);
          *(uint4*)(U.s.xb + r * 1544 + c16 * 8) = tmp[i];
        }
        __syncthreads();
        if (w < 2) {
          f4_t ae = cae, ao = cao;
#pragma unroll
          for (int kk = 16; kk < 48; kk += 2) {
            bfrag_t a0 = *(const bfrag_t*)(U.s.wga + l15 * 1544 + kk * 32 + l4 * 8);
            bfrag_t b0 = *(const bfrag_t*)(U.s.xb + (w * 16 + l15) * 1544 + kk * 32 + l4 * 8);
            bfrag_t a1 = *(const bfrag_t*)(U.s.wga + l15 * 1544 + (kk + 1) * 32 + l4 * 8);
            bfrag_t b1 = *(const bfrag_t*)(U.s.xb + (w * 16 + l15) * 1544 + (kk + 1) * 32 + l4 * 8);
            ae = __builtin_amdgcn_mfma_f32_16x16x32_bf16(a0, b0, ae, 0, 0, 0);
            ao = __builtin_amdgcn_mfma_f32_16x16x32_bf16(a1, b1, ao, 0, 0, 0);
          }
#pragma unroll
          for (int r = 0; r < 4; ++r)
            U.s.gl[l4 * 4 + r][w * 16 + l15] = ae[r] + ao[r];
        }
      }
      __syncthreads();
      if (tid < 128) {
        float gi = U.s.gl[ouo][ob] + xg0;
        float gf = U.s.gl[4 + ouo][ob] + xg1;
        float gg = U.s.gl[8 + ouo][ob] + xg2;
        float go = U.s.gl[12 + ouo][ob] + xg3;
        float cn = sigm(gf) * c_reg + sigm(gi) * ftanh(gg);
        float hn = sigm(go) * ftanh(cn);
        h_reg = hn; c_reg = cn;
        st_f32_coh(DECH + ob * 512 + ou, hn);
        st_f32_coh(DECC + ob * 512 + ou, cn);
        st_u16_coh(ACAT + ((size_t)ob * 31 + t) * 1536 + ou, f2bf(hn));
      }
      arrive8(barB1);
      if (t < 30) {
        wait8(barB1, 128u * (t + 2));
        uint4 pre[8];
#pragma unroll
        for (int i = 0; i < 8; ++i) {
          int idx = tid + i * 256;
          int r = idx >> 6, c16 = idx & 63;
          asm volatile("global_load_dwordx4 %0, %1, off sc0 sc1"
                       : "=v"(pre[i]) : "v"(ACAT + ((size_t)r * 31 + t) * 1536 + c16 * 8));
        }
        asm volatile("s_waitcnt vmcnt(0)" ::: "memory");
#pragma unroll
        for (int i = 0; i < 8; ++i) {
          int idx = tid + i * 256;
          int r = idx >> 6, c16 = idx & 63;
          *(uint4*)(U.s.xb + r * 1544 + c16 * 8) = pre[i];
        }
        __syncthreads();
        if (w < 2) {
          f4_t ae = {0.f, 0.f, 0.f, 0.f}, ao = {0.f, 0.f, 0.f, 0.f};
#pragma unroll
          for (int kk = 0; kk < 16; kk += 2) {
            bfrag_t a0 = *(const bfrag_t*)(U.s.wga + l15 * 1544 + kk * 32 + l4 * 8);
            bfrag_t b0 = *(const bfrag_t*)(U.s.xb + (w * 16 + l15) * 1544 + kk * 32 + l4 * 8);
            bfrag_t a1 = *(const bfrag_t*)(U.s.wga + l15 * 1544 + (kk + 1) * 32 + l4 * 8);
            bfrag_t b1 = *(const bfrag_t*)(U.s.xb + (w * 16 + l15) * 1544 + (kk + 1) * 32 + l4 * 8);
            ae = __builtin_amdgcn_mfma_f32_16x16x32_bf16(a0, b0, ae, 0, 0, 0);
            ao = __builtin_amdgcn_mfma_f32_16x16x32_bf16(a1, b1, ao, 0, 0, 0);
          }
          cae = ae; cao = ao;
        }
      }
    }
  } else {
    // ---------------- attention blocks ----------------
    const int b = bi - 128;
    for (int idx = tid; idx < 64 * 144; idx += 256) {
      int s = idx / 144, c16 = idx - (idx / 144) * 144;
      *(uint4*)(U.a.efg + s * 1160 + c16 * 8) =
          *(const uint4*)(EFG + ((size_t)b * 64 + s) * 1152 + c16 * 8);
    }
    for (int t = 0; t < 31; ++t) {
      wait8(barB1, 128u * (t + 2));   // h(t) ready
      {
        int c = tid * 4;
        const float* hp = (c < 512) ? (DECH + b * 512 + c) : (DECC + b * 512 + (c - 512));
        uint4 hv;
        asm volatile("global_load_dwordx4 %0, %1, off sc0 sc1\n\ts_waitcnt vmcnt(0)"
                     : "=v"(hv) : "v"(hp) : "memory");
        *(uint4*)&U.a.hcl[c] = hv;
      }
      __syncthreads();
      {
        const int sidx = tid >> 2, part = tid & 3;
        const unsigned short* eg = U.a.efg + sidx * 1160 + part * 256;
        const float* d = &U.a.hcl[part * 256];
        float acc = 0.f;
#pragma unroll 8
        for (int k = 0; k < 256; k += 8) {
          uint4 v = *(const uint4*)(eg + k);
          acc += bf2f((unsigned short)(v.x & 0xFFFFu)) * d[k + 0];
          acc += bf2f((unsigned short)(v.x >> 16))     * d[k + 1];
          acc += bf2f((unsigned short)(v.y & 0xFFFFu)) * d[k + 2];
          acc += bf2f((unsigned short)(v.y >> 16))     * d[k + 3];
          acc += bf2f((unsigned short)(v.z & 0xFFFFu)) * d[k + 4];
          acc += bf2f((unsigned short)(v.z >> 16))     * d[k + 5];
          acc += bf2f((unsigned short)(v.w & 0xFFFFu)) * d[k + 6];
          acc += bf2f((unsigned short)(v.w >> 16))     * d[k + 7];
        }
        acc += __shfl_xor(acc, 1);
        acc += __shfl_xor(acc, 2);
        if (part == 0)
          U.a.scl[sidx] = acc + bf2f(U.a.efg[sidx * 1160 + 1024]);  // b_df term
      }
      __syncthreads();
      if (tid < 64) {
        float v = U.a.scl[tid];
        float mx = v;
#pragma unroll
        for (int o = 32; o >= 1; o >>= 1) mx = fmaxf(mx, __shfl_xor(mx, o));
        float e = __expf(v - mx) * mask[b * 64 + tid];
        float sm = e;
#pragma unroll
        for (int o = 32; o >= 1; o >>= 1) sm += __shfl_xor(sm, o);
        U.a.al[tid] = e / sm;
      }
      __syncthreads();
      float c0 = 0.f, c1 = 0.f, c2 = 0.f, c3 = 0.f;
#pragma unroll 8
      for (int tp = 0; tp < 64; ++tp) {
        float a = U.a.al[tp];
        const unsigned short* eo = ENCO + ((size_t)b * 64 + tp) * 1024 + tid;
        c0 += a * bf2f(eo[0]);
        c1 += a * bf2f(eo[256]);
        c2 += a * bf2f(eo[512]);
        c3 += a * bf2f(eo[768]);
      }
      unsigned short* ap = ACAT + ((size_t)b * 31 + t) * 1536 + 512;
      st_u16_coh(ap + tid, f2bf(c0));
      st_u16_coh(ap + tid + 256, f2bf(c1));
      st_u16_coh(ap + tid + 512, f2bf(c2));
      st_u16_coh(ap + tid + 768, f2bf(c3));
      arrive8(barB2);
    }
  }
}

// ============================================================================
extern "C" void kernel_launch(void* const* d_in, const int* in_sizes, int n_in,
                              void* d_out, int out_size, void* d_ws, size_t ws_size,
                              hipStream_t stream) {
  const int*   enc_texts = (const int*)  d_in[0];
  const float* enc_mask  = (const float*)d_in[1];
  const int*   dec_texts = (const int*)  d_in[2];
  const float* enc_emb   = (const float*)d_in[3];
  const float* dec_emb   = (const float*)d_in[4];
  const float* Wih_f = (const float*)d_in[5];
  const float* Whh_f = (const float*)d_in[6];
  const float* b_f   = (const float*)d_in[7];
  const float* Wih_b = (const float*)d_in[8];
  const float* Whh_b = (const float*)d_in[9];
  const float* b_b   = (const float*)d_in[10];
  const float* Wih_d = (const float*)d_in[11];
  const float* Whh_d = (const float*)d_in[12];
  const float* b_d   = (const float*)d_in[13];
  const float* W_h   = (const float*)d_in[14];
  const float* b_h   = (const float*)d_in[15];
  const float* W_c   = (const float*)d_in[16];
  const float* b_c   = (const float*)d_in[17];
  const float* W_df  = (const float*)d_in[18];
  const float* b_df  = (const float*)d_in[19];
  const float* W_ef  = (const float*)d_in[20];
  const float* b_ef  = (const float*)d_in[21];
  const float* W_out = (const float*)d_in[22];
  const float* b_out = (const float*)d_in[23];
  float* out = (float*)d_out;

  char* ws = (char*)d_ws;
  size_t off = 0;
  auto alloc = [&](size_t bytes) {
    char* p = ws + off;
    off += (bytes + 255) & ~(size_t)255;
    return p;
  };
  // --- zero-init group ---
  unsigned short* HBF  = (unsigned short*)alloc((size_t)2 * 2 * 16384 * 2);  // [dir][pp][32*512]
  float* DECH = (float*)alloc((size_t)16384 * 4);
  float* DECC = (float*)alloc((size_t)16384 * 4);
  unsigned short* PRE0 = (unsigned short*)alloc((size_t)32 * 1536 * 2);
  unsigned short* ACAT = (unsigned short*)alloc((size_t)1024 * 1536 * 2);
  unsigned* bar = (unsigned*)alloc(4096);  // enc: +0/+256 (uints); dec: via barD
  unsigned* barD = bar + 512;              // dec B1 @ +512, B2 @ +768
  size_t zbytes = off;
  // --- rest ---
  float* XF = (float*)alloc((size_t)2048 * 2048 * 4);
  float* XB = (float*)alloc((size_t)2048 * 2048 * 4);
  float* XD = (float*)alloc((size_t)1024 * 2048 * 4);
  unsigned short* EFb  = (unsigned short*)alloc((size_t)2048 * 1024 * 2);
  unsigned short* ENCO = (unsigned short*)alloc((size_t)2048 * 1024 * 2);
  unsigned short* EMBB = (unsigned short*)alloc((size_t)2048 * 256 * 2);
  unsigned short* DEMB = (unsigned short*)alloc((size_t)1024 * 256 * 2);
  float* HFIN = (float*)alloc((size_t)4 * 16384 * 4);
  // WT must NOT alias XF/XB: mega_enc's folded transpose writes it while the
  // encoder reads XF/XB concurrently (round-14 bug).  Dedicated allocation.
  float* WT = (float*)alloc((size_t)1152 * 1024 * 4);
  // EFG may alias XF (written by GEMM after mega_enc completes).
  unsigned short* EFG = (unsigned short*)XF;  // 2048 x 1152 bf16
  // W_out bf16 copy (guarded by ws_size)
  unsigned short* WOB = (unsigned short*)alloc((size_t)32000 * 1536 * 2);
  const bool use16 = (off <= ws_size);

  hipMemsetAsync(d_ws, 0, zbytes, stream);

  gather_enc_kernel<<<2048, 64, 0, stream>>>(enc_texts, enc_emb, EMBB);
  gather_dec_kernel<<<1024, 64, 0, stream>>>(dec_texts, dec_emb, DEMB);

  dim3 blk(256);
  gemm_bt_kernel<<<256, blk, 0, stream>>>(EMBB, 256, Wih_f, 256, 0, b_f, XF, 2048, 2048, 256, 16, 0, 0);
  gemm_bt_kernel<<<256, blk, 0, stream>>>(EMBB, 256, Wih_b, 256, 0, b_b, XB, 2048, 2048, 256, 16, 0, 0);
  gemm_bt_kernel<<<128, blk, 0, stream>>>(DEMB, 256, Wih_d, 1280, 0, b_d, XD, 2048, 1024, 256, 8, 0, 0);

  // encoder (64 blocks) + folded W_df transpose workers (160 blocks)
  mega_enc_kernel<<<224, blk, 0, stream>>>(XF, XB, Whh_f, Whh_b, enc_mask, HBF, ENCO, HFIN,
                                           W_df, b_df, WT, bar);

  gemm_bt_kernel<<<128, blk, 0, stream>>>(ENCO, 1024, W_ef, 1024, 0, b_ef, EFb, 1024, 2048, 1024, 16, 0, 1);
  // EFG = EFb @ WT^T  -> bf16, ldc 1152
  gemm_bt_kernel<<<144, blk, 0, stream>>>(EFb, 1024, WT, 1024, 0, nullptr, EFG, 1152, 2048, 1024, 16, 0, 1);

  // decoder (160 blocks) + folded W_out converters (64 blocks)
  mega_dec_kernel<<<224, blk, 0, stream>>>(HFIN, W_h, b_h, W_c, b_c, XD, Wih_d, Whh_d,
                                           EFG, ENCO, enc_mask, DECH, DECC, PRE0, ACAT,
                                           W_out, WOB, use16 ? 1 : 0, barD);

  // logits = [h, ctx] @ W_out^T + b_out  (97.5 GFLOP, 128x128 swizzled)
  if (use16)
    gemm_bt16_kernel<<<2000, blk, 0, stream>>>(ACAT, 1536, WOB, 1536, b_out, out, 32000, 992, 1536, 8, 1);
  else
    gemm_bt_kernel<<<2000, blk, 0, stream>>>(ACAT, 1536, W_out, 1536, 0, b_out, out, 32000, 992, 1536, 8, 1, 0);
}

// Round 16
// 1264.661 us; speedup vs baseline: 1.0550x; 1.0550x over previous
//
#include <hip/hip_runtime.h>
#include <hip/hip_bf16.h>

// ============================================================================
// seq2seq + attention on MI355X.  B=32, Te=64, Td=32 (31 steps), E=256, H=512,
// V=32000.  Round 16: revert to round-13 config (best: 1237us) and re-home
// the folded side-work where it hides:
//   - mega_enc = round-11 encoder (64 blk/dir x 8 units, grid 128) PLUS 128
//     worker blocks (grid 256) doing wdf-transpose then W_out->bf16 conv
//     (294 MB stream hides under the ~340us latency-bound encoder).
//   - mega_dec = round-13 exactly (grid 160, no converters).
//   - bf16 logits GEMM (ws-guarded fallback to fp32-B).
// WT has a dedicated allocation (round-15 lesson: no aliasing with XF/XB).
// ============================================================================

typedef __attribute__((ext_vector_type(8))) short bfrag_t;
typedef __attribute__((ext_vector_type(4))) float f4_t;

static __device__ __forceinline__ float bf2f(unsigned short u) {
  union { float f; unsigned int i; } v; v.i = ((unsigned int)u) << 16; return v.f;
}
static __device__ __forceinline__ unsigned short f2bf(float f) {
  union { float f; unsigned int i; } v; v.f = f;
  unsigned int r = v.i + 0x7FFFu + ((v.i >> 16) & 1u);  // RNE
  return (unsigned short)(r >> 16);
}
static __device__ __forceinline__ unsigned int pack_bf2(float lo, float hi) {
  __hip_bfloat162 h2 = __float22bfloat162_rn(make_float2(lo, hi));
  union { __hip_bfloat162 h; unsigned int u; } cv; cv.h = h2;
  return cv.u;
}
static __device__ __forceinline__ float sigm(float x) {
  return __builtin_amdgcn_rcpf(1.f + __expf(-x));
}
static __device__ __forceinline__ float ftanh(float x) {
  float e = __expf(2.f * x);
  return 1.f - 2.f * __builtin_amdgcn_rcpf(e + 1.f);
}

#define GLDS16(g, l)                                                        \
  __builtin_amdgcn_global_load_lds(                                         \
      (const __attribute__((address_space(1))) void*)(g),                   \
      (__attribute__((address_space(3))) void*)(l), 16, 0, 0)

// ---- device-coherent (agent-scope) access helpers: bypass L2 via sc0 sc1 ----
static __device__ __forceinline__ void st_f32_coh(float* p, float v) {
  asm volatile("global_store_dword %0, %1, off sc0 sc1" :: "v"(p), "v"(v) : "memory");
}
static __device__ __forceinline__ void st_u16_coh(unsigned short* p, unsigned short x) {
  asm volatile("global_store_short %0, %1, off sc0 sc1" :: "v"(p), "v"((unsigned)x) : "memory");
}
static __device__ __forceinline__ float ld_f32_coh(const float* p) {
  float v;
  asm volatile("global_load_dword %0, %1, off sc0 sc1\n\ts_waitcnt vmcnt(0)"
               : "=v"(v) : "v"(p) : "memory");
  return v;
}

// ---------------------------------------------------------------------------
// Decoupled fence-free barrier primitives.
// ---------------------------------------------------------------------------
static __device__ __forceinline__ void arrive8(unsigned* base) {
  __syncthreads();
  if (threadIdx.x == 0)
    __hip_atomic_fetch_add(base + (blockIdx.x & 7) * 32, 1u,
                           __ATOMIC_RELAXED, __HIP_MEMORY_SCOPE_AGENT);
}
static __device__ __forceinline__ void wait8(unsigned* base, unsigned target) {
  if (threadIdx.x < 64) {
    unsigned sum;
    do {
      unsigned v = 0;
      if (threadIdx.x < 8)
        v = __hip_atomic_load(base + threadIdx.x * 32,
                              __ATOMIC_RELAXED, __HIP_MEMORY_SCOPE_AGENT);
      v += __shfl_xor(v, 1);
      v += __shfl_xor(v, 2);
      v += __shfl_xor(v, 4);
      sum = __shfl(v, 0);
      if (sum < target) __builtin_amdgcn_s_sleep(2);
    } while (sum < target);
  }
  __syncthreads();
}
static __device__ __forceinline__ void gbar8(unsigned* base, unsigned target) {
  arrive8(base);
  wait8(base, target);
}

// ---------------------------------------------------------------------------
// C = A(bf16, MxK, lda) @ B(fp32 NxldB rows, +bcol0)^T + bias.  128x128 tile.
// ---------------------------------------------------------------------------
__global__ __launch_bounds__(256) void gemm_bt_kernel(
    const unsigned short* __restrict__ A, int lda,
    const float* __restrict__ B, int ldb, int bcol0,
    const float* __restrict__ bias, void* __restrict__ Cv, int ldc,
    int Mvalid, int K, int Mt, int swz, int obf) {
  __shared__ unsigned short As[128 * 32];
  __shared__ unsigned short Bs[128 * 32];
  int id = blockIdx.x;
  if (swz) { int x = id & 7; id = x * ((int)gridDim.x >> 3) + (id >> 3); }
  const int mb = id % Mt, nb = id / Mt;
  const int m0 = mb * 128, n0 = nb * 128;
  const int tid = threadIdx.x;
  const int w = tid >> 6, lane = tid & 63;
  const int wr = (w >> 1) * 64, wc = (w & 1) * 64;
  const int l15 = lane & 15, l4 = lane >> 4;

  const int arow = w * 16 + (lane >> 2);
  const int acol = (lane & 3) * 8;
  const unsigned short* Ag = A + (size_t)(m0 + arow) * lda + acol;

  const int brow = tid >> 1;
  const int bcol = (tid & 1) * 16;
  const float* Bg = B + (size_t)(n0 + brow) * ldb + bcol0 + bcol;
  unsigned short* Bsw = Bs + brow * 32 + bcol;

  f4_t acc[4][4];
#pragma unroll
  for (int i = 0; i < 4; ++i)
#pragma unroll
    for (int j = 0; j < 4; ++j) {
      acc[i][j].x = 0.f; acc[i][j].y = 0.f; acc[i][j].z = 0.f; acc[i][j].w = 0.f;
    }

  for (int kt = 0; kt < K; kt += 32) {
    GLDS16(Ag + kt, As + w * 512);
    GLDS16(Ag + (size_t)64 * lda + kt, As + (4 + w) * 512);
    float4 q0 = *(const float4*)(Bg + kt);
    float4 q1 = *(const float4*)(Bg + kt + 4);
    float4 q2 = *(const float4*)(Bg + kt + 8);
    float4 q3 = *(const float4*)(Bg + kt + 12);
    union { unsigned int u[8]; uint4 q[2]; } pk;
    pk.u[0] = pack_bf2(q0.x, q0.y); pk.u[1] = pack_bf2(q0.z, q0.w);
    pk.u[2] = pack_bf2(q1.x, q1.y); pk.u[3] = pack_bf2(q1.z, q1.w);
    pk.u[4] = pack_bf2(q2.x, q2.y); pk.u[5] = pack_bf2(q2.z, q2.w);
    pk.u[6] = pack_bf2(q3.x, q3.y); pk.u[7] = pack_bf2(q3.z, q3.w);
    *(uint4*)(Bsw) = pk.q[0];
    *(uint4*)(Bsw + 8) = pk.q[1];
    __syncthreads();
    bfrag_t af[4], bfv[4];
#pragma unroll
    for (int m = 0; m < 4; ++m)
      af[m] = *(const bfrag_t*)(As + (wr + m * 16 + l15) * 32 + l4 * 8);
#pragma unroll
    for (int n = 0; n < 4; ++n)
      bfv[n] = *(const bfrag_t*)(Bs + (wc + n * 16 + l15) * 32 + l4 * 8);
#pragma unroll
    for (int m = 0; m < 4; ++m)
#pragma unroll
      for (int n = 0; n < 4; ++n)
        acc[m][n] = __builtin_amdgcn_mfma_f32_16x16x32_bf16(af[m], bfv[n], acc[m][n], 0, 0, 0);
    __syncthreads();
  }

  const int crb = l4 * 4;
  float* Cf = (float*)Cv;
  unsigned short* Ch = (unsigned short*)Cv;
#pragma unroll
  for (int m = 0; m < 4; ++m)
#pragma unroll
    for (int n = 0; n < 4; ++n)
#pragma unroll
      for (int r = 0; r < 4; ++r) {
        int gr = m0 + wr + m * 16 + crb + r;
        if (gr < Mvalid) {
          int gc = n0 + wc + n * 16 + l15;
          float v = acc[m][n][r] + (bias ? bias[gc] : 0.f);
          if (obf) Ch[(size_t)gr * ldc + gc] = f2bf(v);
          else     Cf[(size_t)gr * ldc + gc] = v;
        }
      }
}

// ---------------------------------------------------------------------------
// bf16 x bf16 variant: C = A @ B^T + bias; both staged via global_load_lds.
// ---------------------------------------------------------------------------
__global__ __launch_bounds__(256) void gemm_bt16_kernel(
    const unsigned short* __restrict__ A, int lda,
    const unsigned short* __restrict__ B, int ldb,
    const float* __restrict__ bias, float* __restrict__ C, int ldc,
    int Mvalid, int K, int Mt, int swz) {
  __shared__ unsigned short As[128 * 32];
  __shared__ unsigned short Bs[128 * 32];
  int id = blockIdx.x;
  if (swz) { int x = id & 7; id = x * ((int)gridDim.x >> 3) + (id >> 3); }
  const int mb = id % Mt, nb = id / Mt;
  const int m0 = mb * 128, n0 = nb * 128;
  const int tid = threadIdx.x;
  const int w = tid >> 6, lane = tid & 63;
  const int wr = (w >> 1) * 64, wc = (w & 1) * 64;
  const int l15 = lane & 15, l4 = lane >> 4;

  const int arow = w * 16 + (lane >> 2);
  const int acol = (lane & 3) * 8;
  const unsigned short* Ag = A + (size_t)(m0 + arow) * lda + acol;
  const unsigned short* Bg = B + (size_t)(n0 + arow) * ldb + acol;

  f4_t acc[4][4];
#pragma unroll
  for (int i = 0; i < 4; ++i)
#pragma unroll
    for (int j = 0; j < 4; ++j) {
      acc[i][j].x = 0.f; acc[i][j].y = 0.f; acc[i][j].z = 0.f; acc[i][j].w = 0.f;
    }

  for (int kt = 0; kt < K; kt += 32) {
    GLDS16(Ag + kt, As + w * 512);
    GLDS16(Ag + (size_t)64 * lda + kt, As + (4 + w) * 512);
    GLDS16(Bg + kt, Bs + w * 512);
    GLDS16(Bg + (size_t)64 * ldb + kt, Bs + (4 + w) * 512);
    __syncthreads();
    bfrag_t af[4], bfv[4];
#pragma unroll
    for (int m = 0; m < 4; ++m)
      af[m] = *(const bfrag_t*)(As + (wr + m * 16 + l15) * 32 + l4 * 8);
#pragma unroll
    for (int n = 0; n < 4; ++n)
      bfv[n] = *(const bfrag_t*)(Bs + (wc + n * 16 + l15) * 32 + l4 * 8);
#pragma unroll
    for (int m = 0; m < 4; ++m)
#pragma unroll
      for (int n = 0; n < 4; ++n)
        acc[m][n] = __builtin_amdgcn_mfma_f32_16x16x32_bf16(af[m], bfv[n], acc[m][n], 0, 0, 0);
    __syncthreads();
  }

  const int crb = l4 * 4;
#pragma unroll
  for (int m = 0; m < 4; ++m)
#pragma unroll
    for (int n = 0; n < 4; ++n)
#pragma unroll
      for (int r = 0; r < 4; ++r) {
        int gr = m0 + wr + m * 16 + crb + r;
        if (gr < Mvalid) {
          int gc = n0 + wc + n * 16 + l15;
          C[(size_t)gr * ldc + gc] = acc[m][n][r] + bias[gc];
        }
      }
}

// ---------------------------------------------------------------------------
// Embedding gathers -> bf16   (unchanged)
// ---------------------------------------------------------------------------
__global__ void gather_enc_kernel(const int* __restrict__ texts,
                                  const float* __restrict__ table,
                                  unsigned short* __restrict__ out) {
  const int row = blockIdx.x;
  const int tok = texts[row];
  const float4 v = *(const float4*)(table + (size_t)tok * 256 + threadIdx.x * 4);
  unsigned short* o = out + (size_t)row * 256 + threadIdx.x * 4;
  o[0] = f2bf(v.x); o[1] = f2bf(v.y); o[2] = f2bf(v.z); o[3] = f2bf(v.w);
}

__global__ void gather_dec_kernel(const int* __restrict__ texts,
                                  const float* __restrict__ table,
                                  unsigned short* __restrict__ out) {
  const int row = blockIdx.x;
  unsigned short* o = out + (size_t)row * 256 + threadIdx.x * 4;
  if (row >= 992) { o[0] = 0; o[1] = 0; o[2] = 0; o[3] = 0; return; }
  const int b = row / 31, t2 = row - b * 31;
  const int tok = texts[b * 32 + t2];
  const float4 v = *(const float4*)(table + (size_t)tok * 256 + threadIdx.x * 4);
  o[0] = f2bf(v.x); o[1] = f2bf(v.y); o[2] = f2bf(v.z); o[3] = f2bf(v.w);
}

// ---------------------------------------------------------------------------
// Encoder megakernel (round-11 structure) + 128 side-worker blocks.
// Grid 256: blocks 0..127 = encoder (64/dir x 8 units);
//           blocks 128..255 = workers: wdf transpose jobs, then W_out->bf16.
// ---------------------------------------------------------------------------
__global__ __launch_bounds__(256) void mega_enc_kernel(
    const float* __restrict__ XF, const float* __restrict__ XB,
    const float* __restrict__ Whh_f, const float* __restrict__ Whh_b,
    const float* __restrict__ mask,
    unsigned short* __restrict__ HBF,   // [dir][pp][32*512] bf16
    unsigned short* __restrict__ ENCO, float* __restrict__ HFIN,
    const float* __restrict__ W_df, const float* __restrict__ b_df,
    float* __restrict__ WT,
    const float* __restrict__ W_out, unsigned short* __restrict__ WOB,
    int do_conv, unsigned* bar) {
  const int bi = blockIdx.x;
  const int tid = threadIdx.x;

  __shared__ union {
    struct {
      unsigned short WA[16 * 520];   // row j=(gate*4+ul), padded stride
      unsigned short HB[32 * 520];   // row = batch
      float Gl[16][33];
    } e;
    struct { float tl[32][33]; } tr;
  } S;

  if (bi >= 128) {
    // ---- side workers: wdf transpose (1025 jobs / 128 blocks), then wout ----
    const int wb = bi - 128;
    for (int job = wb; job < 1025; job += 128) {
      if (job < 1024) {
        const int tx = (job & 31) * 32, ty = (job >> 5) * 32;
        const int r = tid >> 5, c = tid & 31;
#pragma unroll
        for (int i = 0; i < 4; ++i)
          S.tr.tl[r + i * 8][c] = W_df[(size_t)(ty + r + i * 8) * 1024 + tx + c];
        __syncthreads();
#pragma unroll
        for (int i = 0; i < 4; ++i)
          WT[(size_t)(tx + r + i * 8) * 1024 + ty + c] = S.tr.tl[c][r + i * 8];
        __syncthreads();
      } else {
        for (int i = tid; i < 1024; i += 256)
          WT[(size_t)1024 * 1024 + i] = b_df[i];
      }
    }
    if (do_conv) {
      for (size_t base = (size_t)wb * 2048 + tid * 8;
           base < (size_t)32000 * 1536; base += (size_t)128 * 2048) {
        float4 a = *(const float4*)(W_out + base);
        float4 b = *(const float4*)(W_out + base + 4);
        uint4 o;
        o.x = pack_bf2(a.x, a.y); o.y = pack_bf2(a.z, a.w);
        o.z = pack_bf2(b.x, b.y); o.w = pack_bf2(b.z, b.w);
        *(uint4*)(WOB + base) = o;
      }
    }
    return;
  }

  const int dir = bi >> 6;
  const int u0 = (bi & 63) * 8;
  const float* X = dir ? XB : XF;
  const float* W = dir ? Whh_b : Whh_f;
  unsigned short* Hbf = HBF + dir * 32768;
  unsigned* cnt = bar + dir * 256;    // 1 KiB group per direction

  // NOTE: round-11 encoder used WA[32*520]; here 8 units -> 32 gate-rows.
  __shared__ unsigned short WA2[32 * 520];
  __shared__ float Gl2[32][33];

  // preload W: row r (0..31) -> Whh[(r>>3)*512 + u0 + (r&7)]
#pragma unroll
  for (int i = 0; i < 16; ++i) {
    int idx = tid + i * 256;
    int r = idx >> 7, c4 = idx & 127;
    const float4 v = *(const float4*)(W + (size_t)((r >> 3) * 512 + u0 + (r & 7)) * 512 + c4 * 4);
    *(uint2*)(WA2 + r * 520 + c4 * 4) = make_uint2(pack_bf2(v.x, v.y), pack_bf2(v.z, v.w));
  }
  __syncthreads();

  const int w = tid >> 6, lane = tid & 63;
  const int l15 = lane & 15, l4 = lane >> 4;
  const int wrow = (w >> 1) * 16, wcol = (w & 1) * 16;   // wave tile base

  bfrag_t afr[16];
#pragma unroll
  for (int kk = 0; kk < 16; ++kk)
    afr[kk] = *(const bfrag_t*)(WA2 + (wrow + l15) * 520 + kk * 32 + l4 * 8);

  const int ob = tid & 31, ouo = tid >> 5;   // batch, unit offset (0..7)
  const int ou = u0 + ouo;
  float h_reg = 0.f, c_reg = 0.f;

  unsigned tgt = 0;
  for (int s = 0; s < 64; ++s) {
    const int t = dir ? (63 - s) : s;
    const int pp = s & 1;
    const float* xp = X + ((size_t)ob * 64 + t) * 2048 + ou;
    float xg0 = xp[0], xg1 = xp[512], xg2 = xp[1024], xg3 = xp[1536];
    float mval = mask[ob * 64 + t];
    // stage h (bf16, 32 rows x 64 uint4/row) via coherent loads
    const unsigned short* hsrc = Hbf + pp * 16384;
    uint4 tmp[8];
#pragma unroll
    for (int i = 0; i < 8; ++i) {
      int idx = tid + i * 256;
      int r = idx >> 6, c = idx & 63;
      asm volatile("global_load_dwordx4 %0, %1, off sc0 sc1"
                   : "=v"(tmp[i]) : "v"(hsrc + r * 512 + c * 8));
    }
    asm volatile("s_waitcnt vmcnt(0)" ::: "memory");
#pragma unroll
    for (int i = 0; i < 8; ++i) {
      int idx = tid + i * 256;
      int r = idx >> 6, c = idx & 63;
      *(uint4*)(S.e.HB + r * 520 + c * 8) = tmp[i];
    }
    __syncthreads();
    {
      f4_t ae = {0.f, 0.f, 0.f, 0.f}, ao = {0.f, 0.f, 0.f, 0.f};
#pragma unroll
      for (int kk = 0; kk < 16; kk += 2) {
        bfrag_t b0 = *(const bfrag_t*)(S.e.HB + (wcol + l15) * 520 + kk * 32 + l4 * 8);
        bfrag_t b1 = *(const bfrag_t*)(S.e.HB + (wcol + l15) * 520 + (kk + 1) * 32 + l4 * 8);
        ae = __builtin_amdgcn_mfma_f32_16x16x32_bf16(afr[kk], b0, ae, 0, 0, 0);
        ao = __builtin_amdgcn_mfma_f32_16x16x32_bf16(afr[kk + 1], b1, ao, 0, 0, 0);
      }
#pragma unroll
      for (int r = 0; r < 4; ++r)
        Gl2[wrow + l4 * 4 + r][wcol + l15] = ae[r] + ao[r];
    }
    __syncthreads();
    {
      float gi = Gl2[ouo][ob] + xg0;
      float gf = Gl2[8 + ouo][ob] + xg1;
      float gg = Gl2[16 + ouo][ob] + xg2;
      float go = Gl2[24 + ouo][ob] + xg3;
      float cn = sigm(gf) * c_reg + sigm(gi) * ftanh(gg);
      float hn = sigm(go) * ftanh(cn);
      float hmix = mval * hn + (1.f - mval) * h_reg;
      float cmix = mval * cn + (1.f - mval) * c_reg;
      h_reg = hmix; c_reg = cmix;
      ENCO[((size_t)ob * 64 + t) * 1024 + dir * 512 + ou] = f2bf(hmix * mval);
      st_u16_coh(Hbf + (pp ^ 1) * 16384 + ob * 512 + ou, f2bf(hmix));
      if (s == 63) {
        HFIN[dir * 16384 + ob * 512 + ou] = hmix;
        HFIN[(2 + dir) * 16384 + ob * 512 + ou] = cmix;
      }
    }
    if (s < 63) { tgt += 64; gbar8(cnt, tgt); }
  }
}

// ---------------------------------------------------------------------------
// Decoder megakernel (round-13/11).  160 blocks: 0-127 gates, 128-159 attn.
// ---------------------------------------------------------------------------
__global__ __launch_bounds__(256) void mega_dec_kernel(
    const float* __restrict__ HFIN, const float* __restrict__ W_h,
    const float* __restrict__ b_h, const float* __restrict__ W_c,
    const float* __restrict__ b_c, const float* __restrict__ XD,
    const float* __restrict__ Wih_d, const float* __restrict__ Whh_d,
    const unsigned short* __restrict__ EFG, const unsigned short* __restrict__ ENCO,
    const float* __restrict__ mask, float* __restrict__ DECH,
    float* __restrict__ DECC, unsigned short* __restrict__ PRE0,
    unsigned short* __restrict__ ACAT, unsigned* bar) {
  const int bi = blockIdx.x;
  const int tid = threadIdx.x;
  const bool is_attn = (bi >= 128);
  const int u0 = bi * 4;            // gates blocks only
  unsigned* barB1 = bar;            // arrivals: gates (128/step + 128 init)
  unsigned* barB2 = bar + 256;      // arrivals: attn (32/step)

  __shared__ union {
    struct {
      unsigned short wga[16 * 1544];
      unsigned short xb[32 * 1544];
      float gl[16][33];
    } s;
    struct {
      unsigned short efg[64 * 1160];
      float hcl[1024];
      float scl[64];
      float al[64];
    } a;
    struct { float xl[32][132]; float wi[8][132]; } ini;
  } U;

  const int ob = tid & 31, ouo = (tid >> 5) & 3, ou = u0 + ouo;
  const int w = tid >> 6, lane = tid & 63;
  const int l15 = lane & 15, l4 = lane >> 4;

  if (!is_attn) {
    // ---- init: dec_h = relu([hf,hb]@W_h^T+b_h); dec_c likewise (fp32) ----
    {
      const int mat = bi >> 6, j0i = (bi & 63) * 8;
      const int jj = tid >> 5, b = tid & 31;
      const int sr = tid >> 5, sc = (tid & 31) * 4;
      const float* Wm = mat ? W_c : W_h;
      const float* bias = mat ? b_c : b_h;
      const float* x0 = HFIN + (size_t)(mat ? 2 : 0) * 16384;
      const float* x1 = HFIN + (size_t)(mat ? 3 : 1) * 16384;
      float acc = 0.f;
      for (int kc = 0; kc < 1024; kc += 128) {
#pragma unroll
        for (int i = 0; i < 4; ++i) {
          int r = sr + i * 8;
          const float* src = (kc < 512) ? (x0 + r * 512 + kc + sc)
                                        : (x1 + r * 512 + (kc - 512) + sc);
          *(float4*)&U.ini.xl[r][sc] = *(const float4*)src;
        }
        *(float4*)&U.ini.wi[sr][sc] = *(const float4*)(Wm + (size_t)(j0i + sr) * 1024 + kc + sc);
        __syncthreads();
#pragma unroll
        for (int k = 0; k < 128; k += 4) {
          float4 wv = *(const float4*)&U.ini.wi[jj][k];
          float4 xv = *(const float4*)&U.ini.xl[b][k];
          acc += wv.x * xv.x + wv.y * xv.y + wv.z * xv.z + wv.w * xv.w;
        }
        __syncthreads();
      }
      float v = fmaxf(acc + bias[j0i + jj], 0.f);
      if (mat == 0) {
        st_f32_coh(DECH + b * 512 + j0i + jj, v);
        st_u16_coh(PRE0 + (size_t)b * 1536 + j0i + jj, f2bf(v));
      } else {
        st_f32_coh(DECC + b * 512 + j0i + jj, v);
      }
    }
    arrive8(barB1);
    wait8(barB1, 128);

    // ---- preconvert gates A to bf16 LDS ----
#pragma unroll
    for (int i = 0; i < 24; ++i) {
      int idx = tid + i * 256;
      int r = idx / 384, c4 = idx - (idx / 384) * 384;
      int wrow = (r >> 2) * 512 + u0 + (r & 3);
      int c = c4 * 4;
      float4 v;
      if (c < 512) v = *(const float4*)(Whh_d + (size_t)wrow * 512 + c);
      else         v = *(const float4*)(Wih_d + (size_t)wrow * 1280 + 256 + (c - 512));
      *(uint2*)(U.s.wga + r * 1544 + c) = make_uint2(pack_bf2(v.x, v.y), pack_bf2(v.z, v.w));
    }
    float h_reg = 0.f, c_reg = 0.f;
    if (tid < 128) {
      h_reg = ld_f32_coh(DECH + ob * 512 + ou);
      c_reg = ld_f32_coh(DECC + ob * 512 + ou);
    }

    f4_t cae = {0.f, 0.f, 0.f, 0.f}, cao = {0.f, 0.f, 0.f, 0.f};  // carried

    for (int t = 0; t < 31; ++t) {
      float xg0 = 0, xg1 = 0, xg2 = 0, xg3 = 0;
      if (tid < 128) {
        const float* xp = XD + ((size_t)ob * 31 + t) * 2048 + ou;
        xg0 = xp[0]; xg1 = xp[512]; xg2 = xp[1024]; xg3 = xp[1536];
      }
      if (t == 0) {
        uint4 tmp[24];
#pragma unroll
        for (int i = 0; i < 24; ++i) {
          int idx = tid + i * 256;
          int r = idx / 192, c16 = idx - (idx / 192) * 192;
          asm volatile("global_load_dwordx4 %0, %1, off sc0 sc1"
                       : "=v"(tmp[i]) : "v"(PRE0 + (size_t)r * 1536 + c16 * 8));
        }
        asm volatile("s_waitcnt vmcnt(0)" ::: "memory");
#pragma unroll
        for (int i = 0; i < 24; ++i) {
          int idx = tid + i * 256;
          int r = idx / 192, c16 = idx - (idx / 192) * 192;
          *(uint4*)(U.s.xb + r * 1544 + c16 * 8) = tmp[i];
        }
        __syncthreads();
        if (w < 2) {
          f4_t ae = {0.f, 0.f, 0.f, 0.f}, ao = {0.f, 0.f, 0.f, 0.f};
#pragma unroll
          for (int kk = 0; kk < 48; kk += 2) {
            bfrag_t a0 = *(const bfrag_t*)(U.s.wga + l15 * 1544 + kk * 32 + l4 * 8);
            bfrag_t b0 = *(const bfrag_t*)(U.s.xb + (w * 16 + l15) * 1544 + kk * 32 + l4 * 8);
            bfrag_t a1 = *(const bfrag_t*)(U.s.wga + l15 * 1544 + (kk + 1) * 32 + l4 * 8);
            bfrag_t b1 = *(const bfrag_t*)(U.s.xb + (w * 16 + l15) * 1544 + (kk + 1) * 32 + l4 * 8);
            ae = __builtin_amdgcn_mfma_f32_16x16x32_bf16(a0, b0, ae, 0, 0, 0);
            ao = __builtin_amdgcn_mfma_f32_16x16x32_bf16(a1, b1, ao, 0, 0, 0);
          }
#pragma unroll
          for (int r = 0; r < 4; ++r)
            U.s.gl[l4 * 4 + r][w * 16 + l15] = ae[r] + ao[r];
        }
      } else {
        wait8(barB2, 32u * t);
        uint4 tmp[16];
#pragma unroll
        for (int i = 0; i < 16; ++i) {
          int idx = tid + i * 256;
          int r = idx >> 7, c16 = 64 + (idx & 127);
          asm volatile("global_load_dwordx4 %0, %1, off sc0 sc1"
                       : "=v"(tmp[i]) : "v"(ACAT + ((size_t)r * 31 + (t - 1)) * 1536 + c16 * 8));
        }
        asm volatile("s_waitcnt vmcnt(8)" ::: "memory");
#pragma unroll
        for (int i = 0; i < 8; ++i) {
          int idx = tid + i * 256;
          int r = idx >> 7, c16 = 64 + (idx & 127);
          *(uint4*)(U.s.xb + r * 1544 + c16 * 8) = tmp[i];
        }
        asm volatile("s_waitcnt vmcnt(0)" ::: "memory");
#pragma unroll
        for (int i = 8; i < 16; ++i) {
          int idx = tid + i * 256;
          int r = idx >> 7, c16 = 64 + (idx & 127);
          *(uint4*)(U.s.xb + r * 1544 + c16 * 8) = tmp[i];
        }
        __syncthreads();
        if (w < 2) {
          f4_t ae = cae, ao = cao;
#pragma unroll
          for (int kk = 16; kk < 48; kk += 2) {
            bfrag_t a0 = *(const bfrag_t*)(U.s.wga + l15 * 1544 + kk * 32 + l4 * 8);
            bfrag_t b0 = *(const bfrag_t*)(U.s.xb + (w * 16 + l15) * 1544 + kk * 32 + l4 * 8);
            bfrag_t a1 = *(const bfrag_t*)(U.s.wga + l15 * 1544 + (kk + 1) * 32 + l4 * 8);
            bfrag_t b1 = *(const bfrag_t*)(U.s.xb + (w * 16 + l15) * 1544 + (kk + 1) * 32 + l4 * 8);
            ae = __builtin_amdgcn_mfma_f32_16x16x32_bf16(a0, b0, ae, 0, 0, 0);
            ao = __builtin_amdgcn_mfma_f32_16x16x32_bf16(a1, b1, ao, 0, 0, 0);
          }
#pragma unroll
          for (int r = 0; r < 4; ++r)
            U.s.gl[l4 * 4 + r][w * 16 + l15] = ae[r] + ao[r];
        }
      }
      __syncthreads();
      if (tid < 128) {
        float gi = U.s.gl[ouo][ob] + xg0;
        float gf = U.s.gl[4 + ouo][ob] + xg1;
        float gg = U.s.gl[8 + ouo][ob] + xg2;
        float go = U.s.gl[12 + ouo][ob] + xg3;
        float cn = sigm(gf) * c_reg + sigm(gi) * ftanh(gg);
        float hn = sigm(go) * ftanh(cn);
        h_reg = hn; c_reg = cn;
        st_f32_coh(DECH + ob * 512 + ou, hn);
        st_f32_coh(DECC + ob * 512 + ou, cn);
        st_u16_coh(ACAT + ((size_t)ob * 31 + t) * 1536 + ou, f2bf(hn));
      }
      arrive8(barB1);
      if (t < 30) {
        wait8(barB1, 128u * (t + 2));
        uint4 pre[8];
#pragma unroll
        for (int i = 0; i < 8; ++i) {
          int idx = tid + i * 256;
          int r = idx >> 6, c16 = idx & 63;
          asm volatile("global_load_dwordx4 %0, %1, off sc0 sc1"
                       : "=v"(pre[i]) : "v"(ACAT + ((size_t)r * 31 + t) * 1536 + c16 * 8));
        }
        asm volatile("s_waitcnt vmcnt(0)" ::: "memory");
#pragma unroll
        for (int i = 0; i < 8; ++i) {
          int idx = tid + i * 256;
          int r = idx >> 6, c16 = idx & 63;
          *(uint4*)(U.s.xb + r * 1544 + c16 * 8) = pre[i];
        }
        __syncthreads();
        if (w < 2) {
          f4_t ae = {0.f, 0.f, 0.f, 0.f}, ao = {0.f, 0.f, 0.f, 0.f};
#pragma unroll
          for (int kk = 0; kk < 16; kk += 2) {
            bfrag_t a0 = *(const bfrag_t*)(U.s.wga + l15 * 1544 + kk * 32 + l4 * 8);
            bfrag_t b0 = *(const bfrag_t*)(U.s.xb + (w * 16 + l15) * 1544 + kk * 32 + l4 * 8);
            bfrag_t a1 = *(const bfrag_t*)(U.s.wga + l15 * 1544 + (kk + 1) * 32 + l4 * 8);
            bfrag_t b1 = *(const bfrag_t*)(U.s.xb + (w * 16 + l15) * 1544 + (kk + 1) * 32 + l4 * 8);
            ae = __builtin_amdgcn_mfma_f32_16x16x32_bf16(a0, b0, ae, 0, 0, 0);
            ao = __builtin_amdgcn_mfma_f32_16x16x32_bf16(a1, b1, ao, 0, 0, 0);
          }
          cae = ae; cao = ao;
        }
      }
    }
  } else {
    // ---------------- attention blocks ----------------
    const int b = bi - 128;
    for (int idx = tid; idx < 64 * 144; idx += 256) {
      int s = idx / 144, c16 = idx - (idx / 144) * 144;
      *(uint4*)(U.a.efg + s * 1160 + c16 * 8) =
          *(const uint4*)(EFG + ((size_t)b * 64 + s) * 1152 + c16 * 8);
    }
    for (int t = 0; t < 31; ++t) {
      wait8(barB1, 128u * (t + 2));   // h(t) ready
      {
        int c = tid * 4;
        const float* hp = (c < 512) ? (DECH + b * 512 + c) : (DECC + b * 512 + (c - 512));
        uint4 hv;
        asm volatile("global_load_dwordx4 %0, %1, off sc0 sc1\n\ts_waitcnt vmcnt(0)"
                     : "=v"(hv) : "v"(hp) : "memory");
        *(uint4*)&U.a.hcl[c] = hv;
      }
      __syncthreads();
      {
        const int sidx = tid >> 2, part = tid & 3;
        const unsigned short* eg = U.a.efg + sidx * 1160 + part * 256;
        const float* d = &U.a.hcl[part * 256];
        float acc = 0.f;
#pragma unroll 8
        for (int k = 0; k < 256; k += 8) {
          uint4 v = *(const uint4*)(eg + k);
          acc += bf2f((unsigned short)(v.x & 0xFFFFu)) * d[k + 0];
          acc += bf2f((unsigned short)(v.x >> 16))     * d[k + 1];
          acc += bf2f((unsigned short)(v.y & 0xFFFFu)) * d[k + 2];
          acc += bf2f((unsigned short)(v.y >> 16))     * d[k + 3];
          acc += bf2f((unsigned short)(v.z & 0xFFFFu)) * d[k + 4];
          acc += bf2f((unsigned short)(v.z >> 16))     * d[k + 5];
          acc += bf2f((unsigned short)(v.w & 0xFFFFu)) * d[k + 6];
          acc += bf2f((unsigned short)(v.w >> 16))     * d[k + 7];
        }
        acc += __shfl_xor(acc, 1);
        acc += __shfl_xor(acc, 2);
        if (part == 0)
          U.a.scl[sidx] = acc + bf2f(U.a.efg[sidx * 1160 + 1024]);  // b_df term
      }
      __syncthreads();
      if (tid < 64) {
        float v = U.a.scl[tid];
        float mx = v;
#pragma unroll
        for (int o = 32; o >= 1; o >>= 1) mx = fmaxf(mx, __shfl_xor(mx, o));
        float e = __expf(v - mx) * mask[b * 64 + tid];
        float sm = e;
#pragma unroll
        for (int o = 32; o >= 1; o >>= 1) sm += __shfl_xor(sm, o);
        U.a.al[tid] = e / sm;
      }
      __syncthreads();
      float c0 = 0.f, c1 = 0.f, c2 = 0.f, c3 = 0.f;
#pragma unroll 8
      for (int tp = 0; tp < 64; ++tp) {
        float a = U.a.al[tp];
        const unsigned short* eo = ENCO + ((size_t)b * 64 + tp) * 1024 + tid;
        c0 += a * bf2f(eo[0]);
        c1 += a * bf2f(eo[256]);
        c2 += a * bf2f(eo[512]);
        c3 += a * bf2f(eo[768]);
      }
      unsigned short* ap = ACAT + ((size_t)b * 31 + t) * 1536 + 512;
      st_u16_coh(ap + tid, f2bf(c0));
      st_u16_coh(ap + tid + 256, f2bf(c1));
      st_u16_coh(ap + tid + 512, f2bf(c2));
      st_u16_coh(ap + tid + 768, f2bf(c3));
      arrive8(barB2);
    }
  }
}

// ============================================================================
extern "C" void kernel_launch(void* const* d_in, const int* in_sizes, int n_in,
                              void* d_out, int out_size, void* d_ws, size_t ws_size,
                              hipStream_t stream) {
  const int*   enc_texts = (const int*)  d_in[0];
  const float* enc_mask  = (const float*)d_in[1];
  const int*   dec_texts = (const int*)  d_in[2];
  const float* enc_emb   = (const float*)d_in[3];
  const float* dec_emb   = (const float*)d_in[4];
  const float* Wih_f = (const float*)d_in[5];
  const float* Whh_f = (const float*)d_in[6];
  const float* b_f   = (const float*)d_in[7];
  const float* Wih_b = (const float*)d_in[8];
  const float* Whh_b = (const float*)d_in[9];
  const float* b_b   = (const float*)d_in[10];
  const float* Wih_d = (const float*)d_in[11];
  const float* Whh_d = (const float*)d_in[12];
  const float* b_d   = (const float*)d_in[13];
  const float* W_h   = (const float*)d_in[14];
  const float* b_h   = (const float*)d_in[15];
  const float* W_c   = (const float*)d_in[16];
  const float* b_c   = (const float*)d_in[17];
  const float* W_df  = (const float*)d_in[18];
  const float* b_df  = (const float*)d_in[19];
  const float* W_ef  = (const float*)d_in[20];
  const float* b_ef  = (const float*)d_in[21];
  const float* W_out = (const float*)d_in[22];
  const float* b_out = (const float*)d_in[23];
  float* out = (float*)d_out;

  char* ws = (char*)d_ws;
  size_t off = 0;
  auto alloc = [&](size_t bytes) {
    char* p = ws + off;
    off += (bytes + 255) & ~(size_t)255;
    return p;
  };
  // --- zero-init group ---
  unsigned short* HBF  = (unsigned short*)alloc((size_t)2 * 2 * 16384 * 2);  // [dir][pp][32*512]
  float* DECH = (float*)alloc((size_t)16384 * 4);
  float* DECC = (float*)alloc((size_t)16384 * 4);
  unsigned short* PRE0 = (unsigned short*)alloc((size_t)32 * 1536 * 2);
  unsigned short* ACAT = (unsigned short*)alloc((size_t)1024 * 1536 * 2);
  unsigned* bar = (unsigned*)alloc(4096);  // enc: +0/+256 (uints); dec: via barD
  unsigned* barD = bar + 512;              // dec B1 @ +512, B2 @ +768
  size_t zbytes = off;
  // --- rest ---
  float* XF = (float*)alloc((size_t)2048 * 2048 * 4);
  float* XB = (float*)alloc((size_t)2048 * 2048 * 4);
  float* XD = (float*)alloc((size_t)1024 * 2048 * 4);
  unsigned short* EFb  = (unsigned short*)alloc((size_t)2048 * 1024 * 2);
  unsigned short* ENCO = (unsigned short*)alloc((size_t)2048 * 1024 * 2);
  unsigned short* EMBB = (unsigned short*)alloc((size_t)2048 * 256 * 2);
  unsigned short* DEMB = (unsigned short*)alloc((size_t)1024 * 256 * 2);
  float* HFIN = (float*)alloc((size_t)4 * 16384 * 4);
  // WT: dedicated allocation (no aliasing with XF/XB — written concurrently
  // with the encoder by the folded workers; round-14/15 lesson).
  float* WT = (float*)alloc((size_t)1152 * 1024 * 4);
  // EFG may alias XF (written by GEMM after mega_enc completes).
  unsigned short* EFG = (unsigned short*)XF;  // 2048 x 1152 bf16
  // W_out bf16 copy (guarded by ws_size)
  unsigned short* WOB = (unsigned short*)alloc((size_t)32000 * 1536 * 2);
  const bool use16 = (off <= ws_size);

  hipMemsetAsync(d_ws, 0, zbytes, stream);

  gather_enc_kernel<<<2048, 64, 0, stream>>>(enc_texts, enc_emb, EMBB);
  gather_dec_kernel<<<1024, 64, 0, stream>>>(dec_texts, dec_emb, DEMB);

  dim3 blk(256);
  gemm_bt_kernel<<<256, blk, 0, stream>>>(EMBB, 256, Wih_f, 256, 0, b_f, XF, 2048, 2048, 256, 16, 0, 0);
  gemm_bt_kernel<<<256, blk, 0, stream>>>(EMBB, 256, Wih_b, 256, 0, b_b, XB, 2048, 2048, 256, 16, 0, 0);
  gemm_bt_kernel<<<128, blk, 0, stream>>>(DEMB, 256, Wih_d, 1280, 0, b_d, XD, 2048, 1024, 256, 8, 0, 0);

  // encoder (128 blocks) + side workers (128 blocks: wdf transpose, wout conv)
  mega_enc_kernel<<<256, blk, 0, stream>>>(XF, XB, Whh_f, Whh_b, enc_mask, HBF, ENCO, HFIN,
                                           W_df, b_df, WT, W_out, WOB, use16 ? 1 : 0, bar);

  gemm_bt_kernel<<<128, blk, 0, stream>>>(ENCO, 1024, W_ef, 1024, 0, b_ef, EFb, 1024, 2048, 1024, 16, 0, 1);
  // EFG = EFb @ WT^T  -> bf16, ldc 1152
  gemm_bt_kernel<<<144, blk, 0, stream>>>(EFb, 1024, WT, 1024, 0, nullptr, EFG, 1152, 2048, 1024, 16, 0, 1);

  // decoder (160 blocks, round-13 structure)
  mega_dec_kernel<<<160, blk, 0, stream>>>(HFIN, W_h, b_h, W_c, b_c, XD, Wih_d, Whh_d,
                                           EFG, ENCO, enc_mask, DECH, DECC, PRE0, ACAT, barD);

  // logits = [h, ctx] @ W_out^T + b_out  (97.5 GFLOP, 128x128 swizzled)
  if (use16)
    gemm_bt16_kernel<<<2000, blk, 0, stream>>>(ACAT, 1536, WOB, 1536, b_out, out, 32000, 992, 1536, 8, 1);
  else
    gemm_bt_kernel<<<2000, blk, 0, stream>>>(ACAT, 1536, W_out, 1536, 0, b_out, out, 32000, 992, 1536, 8, 1, 0);
}

// Round 17
// 1192.837 us; speedup vs baseline: 1.1185x; 1.0602x over previous
//
#include <hip/hip_runtime.h>
#include <hip/hip_bf16.h>

// ============================================================================
// seq2seq + attention on MI355X.  B=32, Te=64, Td=32 (31 steps), E=256, H=512,
// V=32000.  Round 17: recombination of measured-best components:
//   - encoder + serial wdf transpose = round 13 exactly (grid 128 + 1025).
//   - mega_dec = round 15's (round-11 structure + 64 W_out->bf16 converter
//     blocks, grid 224): conv hides under decoder, measured net -33us.
//   - bf16 logits GEMM (ws-guarded), 128x128 XCD-swizzled = round 13.
// ============================================================================

typedef __attribute__((ext_vector_type(8))) short bfrag_t;
typedef __attribute__((ext_vector_type(4))) float f4_t;

static __device__ __forceinline__ float bf2f(unsigned short u) {
  union { float f; unsigned int i; } v; v.i = ((unsigned int)u) << 16; return v.f;
}
static __device__ __forceinline__ unsigned short f2bf(float f) {
  union { float f; unsigned int i; } v; v.f = f;
  unsigned int r = v.i + 0x7FFFu + ((v.i >> 16) & 1u);  // RNE
  return (unsigned short)(r >> 16);
}
static __device__ __forceinline__ unsigned int pack_bf2(float lo, float hi) {
  __hip_bfloat162 h2 = __float22bfloat162_rn(make_float2(lo, hi));
  union { __hip_bfloat162 h; unsigned int u; } cv; cv.h = h2;
  return cv.u;
}
static __device__ __forceinline__ float sigm(float x) {
  return __builtin_amdgcn_rcpf(1.f + __expf(-x));
}
static __device__ __forceinline__ float ftanh(float x) {
  float e = __expf(2.f * x);
  return 1.f - 2.f * __builtin_amdgcn_rcpf(e + 1.f);
}

#define GLDS16(g, l)                                                        \
  __builtin_amdgcn_global_load_lds(                                         \
      (const __attribute__((address_space(1))) void*)(g),                   \
      (__attribute__((address_space(3))) void*)(l), 16, 0, 0)

// ---- device-coherent (agent-scope) access helpers: bypass L2 via sc0 sc1 ----
static __device__ __forceinline__ void st_f32_coh(float* p, float v) {
  asm volatile("global_store_dword %0, %1, off sc0 sc1" :: "v"(p), "v"(v) : "memory");
}
static __device__ __forceinline__ void st_u16_coh(unsigned short* p, unsigned short x) {
  asm volatile("global_store_short %0, %1, off sc0 sc1" :: "v"(p), "v"((unsigned)x) : "memory");
}
static __device__ __forceinline__ float ld_f32_coh(const float* p) {
  float v;
  asm volatile("global_load_dword %0, %1, off sc0 sc1\n\ts_waitcnt vmcnt(0)"
               : "=v"(v) : "v"(p) : "memory");
  return v;
}

// ---------------------------------------------------------------------------
// Decoupled fence-free barrier primitives.
// ---------------------------------------------------------------------------
static __device__ __forceinline__ void arrive8(unsigned* base) {
  __syncthreads();
  if (threadIdx.x == 0)
    __hip_atomic_fetch_add(base + (blockIdx.x & 7) * 32, 1u,
                           __ATOMIC_RELAXED, __HIP_MEMORY_SCOPE_AGENT);
}
static __device__ __forceinline__ void wait8(unsigned* base, unsigned target) {
  if (threadIdx.x < 64) {
    unsigned sum;
    do {
      unsigned v = 0;
      if (threadIdx.x < 8)
        v = __hip_atomic_load(base + threadIdx.x * 32,
                              __ATOMIC_RELAXED, __HIP_MEMORY_SCOPE_AGENT);
      v += __shfl_xor(v, 1);
      v += __shfl_xor(v, 2);
      v += __shfl_xor(v, 4);
      sum = __shfl(v, 0);
      if (sum < target) __builtin_amdgcn_s_sleep(2);
    } while (sum < target);
  }
  __syncthreads();
}
static __device__ __forceinline__ void gbar8(unsigned* base, unsigned target) {
  arrive8(base);
  wait8(base, target);
}

// ---------------------------------------------------------------------------
// C = A(bf16, MxK, lda) @ B(fp32 NxldB rows, +bcol0)^T + bias.  128x128 tile.
// ---------------------------------------------------------------------------
__global__ __launch_bounds__(256) void gemm_bt_kernel(
    const unsigned short* __restrict__ A, int lda,
    const float* __restrict__ B, int ldb, int bcol0,
    const float* __restrict__ bias, void* __restrict__ Cv, int ldc,
    int Mvalid, int K, int Mt, int swz, int obf) {
  __shared__ unsigned short As[128 * 32];
  __shared__ unsigned short Bs[128 * 32];
  int id = blockIdx.x;
  if (swz) { int x = id & 7; id = x * ((int)gridDim.x >> 3) + (id >> 3); }
  const int mb = id % Mt, nb = id / Mt;
  const int m0 = mb * 128, n0 = nb * 128;
  const int tid = threadIdx.x;
  const int w = tid >> 6, lane = tid & 63;
  const int wr = (w >> 1) * 64, wc = (w & 1) * 64;
  const int l15 = lane & 15, l4 = lane >> 4;

  const int arow = w * 16 + (lane >> 2);
  const int acol = (lane & 3) * 8;
  const unsigned short* Ag = A + (size_t)(m0 + arow) * lda + acol;

  const int brow = tid >> 1;
  const int bcol = (tid & 1) * 16;
  const float* Bg = B + (size_t)(n0 + brow) * ldb + bcol0 + bcol;
  unsigned short* Bsw = Bs + brow * 32 + bcol;

  f4_t acc[4][4];
#pragma unroll
  for (int i = 0; i < 4; ++i)
#pragma unroll
    for (int j = 0; j < 4; ++j) {
      acc[i][j].x = 0.f; acc[i][j].y = 0.f; acc[i][j].z = 0.f; acc[i][j].w = 0.f;
    }

  for (int kt = 0; kt < K; kt += 32) {
    GLDS16(Ag + kt, As + w * 512);
    GLDS16(Ag + (size_t)64 * lda + kt, As + (4 + w) * 512);
    float4 q0 = *(const float4*)(Bg + kt);
    float4 q1 = *(const float4*)(Bg + kt + 4);
    float4 q2 = *(const float4*)(Bg + kt + 8);
    float4 q3 = *(const float4*)(Bg + kt + 12);
    union { unsigned int u[8]; uint4 q[2]; } pk;
    pk.u[0] = pack_bf2(q0.x, q0.y); pk.u[1] = pack_bf2(q0.z, q0.w);
    pk.u[2] = pack_bf2(q1.x, q1.y); pk.u[3] = pack_bf2(q1.z, q1.w);
    pk.u[4] = pack_bf2(q2.x, q2.y); pk.u[5] = pack_bf2(q2.z, q2.w);
    pk.u[6] = pack_bf2(q3.x, q3.y); pk.u[7] = pack_bf2(q3.z, q3.w);
    *(uint4*)(Bsw) = pk.q[0];
    *(uint4*)(Bsw + 8) = pk.q[1];
    __syncthreads();
    bfrag_t af[4], bfv[4];
#pragma unroll
    for (int m = 0; m < 4; ++m)
      af[m] = *(const bfrag_t*)(As + (wr + m * 16 + l15) * 32 + l4 * 8);
#pragma unroll
    for (int n = 0; n < 4; ++n)
      bfv[n] = *(const bfrag_t*)(Bs + (wc + n * 16 + l15) * 32 + l4 * 8);
#pragma unroll
    for (int m = 0; m < 4; ++m)
#pragma unroll
      for (int n = 0; n < 4; ++n)
        acc[m][n] = __builtin_amdgcn_mfma_f32_16x16x32_bf16(af[m], bfv[n], acc[m][n], 0, 0, 0);
    __syncthreads();
  }

  const int crb = l4 * 4;
  float* Cf = (float*)Cv;
  unsigned short* Ch = (unsigned short*)Cv;
#pragma unroll
  for (int m = 0; m < 4; ++m)
#pragma unroll
    for (int n = 0; n < 4; ++n)
#pragma unroll
      for (int r = 0; r < 4; ++r) {
        int gr = m0 + wr + m * 16 + crb + r;
        if (gr < Mvalid) {
          int gc = n0 + wc + n * 16 + l15;
          float v = acc[m][n][r] + (bias ? bias[gc] : 0.f);
          if (obf) Ch[(size_t)gr * ldc + gc] = f2bf(v);
          else     Cf[(size_t)gr * ldc + gc] = v;
        }
      }
}

// ---------------------------------------------------------------------------
// bf16 x bf16 variant: C = A @ B^T + bias; both staged via global_load_lds.
// ---------------------------------------------------------------------------
__global__ __launch_bounds__(256) void gemm_bt16_kernel(
    const unsigned short* __restrict__ A, int lda,
    const unsigned short* __restrict__ B, int ldb,
    const float* __restrict__ bias, float* __restrict__ C, int ldc,
    int Mvalid, int K, int Mt, int swz) {
  __shared__ unsigned short As[128 * 32];
  __shared__ unsigned short Bs[128 * 32];
  int id = blockIdx.x;
  if (swz) { int x = id & 7; id = x * ((int)gridDim.x >> 3) + (id >> 3); }
  const int mb = id % Mt, nb = id / Mt;
  const int m0 = mb * 128, n0 = nb * 128;
  const int tid = threadIdx.x;
  const int w = tid >> 6, lane = tid & 63;
  const int wr = (w >> 1) * 64, wc = (w & 1) * 64;
  const int l15 = lane & 15, l4 = lane >> 4;

  const int arow = w * 16 + (lane >> 2);
  const int acol = (lane & 3) * 8;
  const unsigned short* Ag = A + (size_t)(m0 + arow) * lda + acol;
  const unsigned short* Bg = B + (size_t)(n0 + arow) * ldb + acol;

  f4_t acc[4][4];
#pragma unroll
  for (int i = 0; i < 4; ++i)
#pragma unroll
    for (int j = 0; j < 4; ++j) {
      acc[i][j].x = 0.f; acc[i][j].y = 0.f; acc[i][j].z = 0.f; acc[i][j].w = 0.f;
    }

  for (int kt = 0; kt < K; kt += 32) {
    GLDS16(Ag + kt, As + w * 512);
    GLDS16(Ag + (size_t)64 * lda + kt, As + (4 + w) * 512);
    GLDS16(Bg + kt, Bs + w * 512);
    GLDS16(Bg + (size_t)64 * ldb + kt, Bs + (4 + w) * 512);
    __syncthreads();
    bfrag_t af[4], bfv[4];
#pragma unroll
    for (int m = 0; m < 4; ++m)
      af[m] = *(const bfrag_t*)(As + (wr + m * 16 + l15) * 32 + l4 * 8);
#pragma unroll
    for (int n = 0; n < 4; ++n)
      bfv[n] = *(const bfrag_t*)(Bs + (wc + n * 16 + l15) * 32 + l4 * 8);
#pragma unroll
    for (int m = 0; m < 4; ++m)
#pragma unroll
      for (int n = 0; n < 4; ++n)
        acc[m][n] = __builtin_amdgcn_mfma_f32_16x16x32_bf16(af[m], bfv[n], acc[m][n], 0, 0, 0);
    __syncthreads();
  }

  const int crb = l4 * 4;
#pragma unroll
  for (int m = 0; m < 4; ++m)
#pragma unroll
    for (int n = 0; n < 4; ++n)
#pragma unroll
      for (int r = 0; r < 4; ++r) {
        int gr = m0 + wr + m * 16 + crb + r;
        if (gr < Mvalid) {
          int gc = n0 + wc + n * 16 + l15;
          C[(size_t)gr * ldc + gc] = acc[m][n][r] + bias[gc];
        }
      }
}

// ---------------------------------------------------------------------------
// Embedding gathers -> bf16
// ---------------------------------------------------------------------------
__global__ void gather_enc_kernel(const int* __restrict__ texts,
                                  const float* __restrict__ table,
                                  unsigned short* __restrict__ out) {
  const int row = blockIdx.x;
  const int tok = texts[row];
  const float4 v = *(const float4*)(table + (size_t)tok * 256 + threadIdx.x * 4);
  unsigned short* o = out + (size_t)row * 256 + threadIdx.x * 4;
  o[0] = f2bf(v.x); o[1] = f2bf(v.y); o[2] = f2bf(v.z); o[3] = f2bf(v.w);
}

__global__ void gather_dec_kernel(const int* __restrict__ texts,
                                  const float* __restrict__ table,
                                  unsigned short* __restrict__ out) {
  const int row = blockIdx.x;
  unsigned short* o = out + (size_t)row * 256 + threadIdx.x * 4;
  if (row >= 992) { o[0] = 0; o[1] = 0; o[2] = 0; o[3] = 0; return; }
  const int b = row / 31, t2 = row - b * 31;
  const int tok = texts[b * 32 + t2];
  const float4 v = *(const float4*)(table + (size_t)tok * 256 + threadIdx.x * 4);
  o[0] = f2bf(v.x); o[1] = f2bf(v.y); o[2] = f2bf(v.z); o[3] = f2bf(v.w);
}

// ---------------------------------------------------------------------------
// W_dfT[n][j] = W_df[j][n] (1024x1024), row 1024 = b_df.  (serial, r13)
// ---------------------------------------------------------------------------
__global__ __launch_bounds__(256) void wdf_t_kernel(
    const float* __restrict__ W_df, const float* __restrict__ b_df,
    float* __restrict__ WT) {
  const int bid = blockIdx.x;
  if (bid < 1024) {
    __shared__ float tl[32][33];
    const int tx = (bid & 31) * 32, ty = (bid >> 5) * 32;
    const int r = threadIdx.x >> 5, c = threadIdx.x & 31;
#pragma unroll
    for (int i = 0; i < 4; ++i)
      tl[r + i * 8][c] = W_df[(size_t)(ty + r + i * 8) * 1024 + tx + c];
    __syncthreads();
#pragma unroll
    for (int i = 0; i < 4; ++i)
      WT[(size_t)(tx + r + i * 8) * 1024 + ty + c] = tl[c][r + i * 8];
  } else {
    for (int i = threadIdx.x; i < 1024; i += 256)
      WT[(size_t)1024 * 1024 + i] = b_df[i];
  }
}

// ---------------------------------------------------------------------------
// Encoder megakernel (MFMA).  64 blocks/dir x 8 units.   (round 13 exactly)
// ---------------------------------------------------------------------------
__global__ __launch_bounds__(256) void mega_enc_kernel(
    const float* __restrict__ XF, const float* __restrict__ XB,
    const float* __restrict__ Whh_f, const float* __restrict__ Whh_b,
    const float* __restrict__ mask,
    unsigned short* __restrict__ HBF,   // [dir][pp][32*512] bf16
    unsigned short* __restrict__ ENCO, float* __restrict__ HFIN,
    unsigned* bar) {
  const int bi = blockIdx.x;          // 0..127
  const int dir = bi >> 6;
  const int u0 = (bi & 63) * 8;
  const int tid = threadIdx.x;
  const float* X = dir ? XB : XF;
  const float* W = dir ? Whh_b : Whh_f;
  unsigned short* Hbf = HBF + dir * 32768;
  unsigned* cnt = bar + dir * 256;    // 1 KiB group per direction

  __shared__ unsigned short WA[32 * 520];   // 32 gate-rows: (gate*8+ul)
  __shared__ unsigned short HB[32 * 520];   // row = batch
  __shared__ float Gl[32][33];

  // preload W: row r -> Whh[(r>>3)*512 + u0 + (r&7)]
#pragma unroll
  for (int i = 0; i < 16; ++i) {
    int idx = tid + i * 256;
    int r = idx >> 7, c4 = idx & 127;
    const float4 v = *(const float4*)(W + (size_t)((r >> 3) * 512 + u0 + (r & 7)) * 512 + c4 * 4);
    *(uint2*)(WA + r * 520 + c4 * 4) = make_uint2(pack_bf2(v.x, v.y), pack_bf2(v.z, v.w));
  }
  __syncthreads();

  const int w = tid >> 6, lane = tid & 63;
  const int l15 = lane & 15, l4 = lane >> 4;
  const int wrow = (w >> 1) * 16, wcol = (w & 1) * 16;   // wave tile base

  bfrag_t afr[16];
#pragma unroll
  for (int kk = 0; kk < 16; ++kk)
    afr[kk] = *(const bfrag_t*)(WA + (wrow + l15) * 520 + kk * 32 + l4 * 8);

  const int ob = tid & 31, ouo = tid >> 5;   // batch, unit offset (0..7)
  const int ou = u0 + ouo;
  float h_reg = 0.f, c_reg = 0.f;

  unsigned tgt = 0;
  for (int s = 0; s < 64; ++s) {
    const int t = dir ? (63 - s) : s;
    const int pp = s & 1;
    const float* xp = X + ((size_t)ob * 64 + t) * 2048 + ou;
    float xg0 = xp[0], xg1 = xp[512], xg2 = xp[1024], xg3 = xp[1536];
    float mval = mask[ob * 64 + t];
    // stage h (bf16, 32 rows x 64 uint4/row) via coherent loads
    const unsigned short* hsrc = Hbf + pp * 16384;
    uint4 tmp[8];
#pragma unroll
    for (int i = 0; i < 8; ++i) {
      int idx = tid + i * 256;
      int r = idx >> 6, c = idx & 63;
      asm volatile("global_load_dwordx4 %0, %1, off sc0 sc1"
                   : "=v"(tmp[i]) : "v"(hsrc + r * 512 + c * 8));
    }
    asm volatile("s_waitcnt vmcnt(0)" ::: "memory");
#pragma unroll
    for (int i = 0; i < 8; ++i) {
      int idx = tid + i * 256;
      int r = idx >> 6, c = idx & 63;
      *(uint4*)(HB + r * 520 + c * 8) = tmp[i];
    }
    __syncthreads();
    {
      f4_t ae = {0.f, 0.f, 0.f, 0.f}, ao = {0.f, 0.f, 0.f, 0.f};
#pragma unroll
      for (int kk = 0; kk < 16; kk += 2) {
        bfrag_t b0 = *(const bfrag_t*)(HB + (wcol + l15) * 520 + kk * 32 + l4 * 8);
        bfrag_t b1 = *(const bfrag_t*)(HB + (wcol + l15) * 520 + (kk + 1) * 32 + l4 * 8);
        ae = __builtin_amdgcn_mfma_f32_16x16x32_bf16(afr[kk], b0, ae, 0, 0, 0);
        ao = __builtin_amdgcn_mfma_f32_16x16x32_bf16(afr[kk + 1], b1, ao, 0, 0, 0);
      }
#pragma unroll
      for (int r = 0; r < 4; ++r)
        Gl[wrow + l4 * 4 + r][wcol + l15] = ae[r] + ao[r];
    }
    __syncthreads();
    {
      float gi = Gl[ouo][ob] + xg0;
      float gf = Gl[8 + ouo][ob] + xg1;
      float gg = Gl[16 + ouo][ob] + xg2;
      float go = Gl[24 + ouo][ob] + xg3;
      float cn = sigm(gf) * c_reg + sigm(gi) * ftanh(gg);
      float hn = sigm(go) * ftanh(cn);
      float hmix = mval * hn + (1.f - mval) * h_reg;
      float cmix = mval * cn + (1.f - mval) * c_reg;
      h_reg = hmix; c_reg = cmix;
      ENCO[((size_t)ob * 64 + t) * 1024 + dir * 512 + ou] = f2bf(hmix * mval);
      st_u16_coh(Hbf + (pp ^ 1) * 16384 + ob * 512 + ou, f2bf(hmix));
      if (s == 63) {
        HFIN[dir * 16384 + ob * 512 + ou] = hmix;
        HFIN[(2 + dir) * 16384 + ob * 512 + ou] = cmix;
      }
    }
    if (s < 63) { tgt += 64; gbar8(cnt, tgt); }
  }
}

// ---------------------------------------------------------------------------
// Decoder megakernel (MFMA) + folded W_out->bf16 converters.  (round 15)
// Grid 224: 0-127 gates, 128-159 attention, 160-223 converters.
// ---------------------------------------------------------------------------
__global__ __launch_bounds__(256) void mega_dec_kernel(
    const float* __restrict__ HFIN, const float* __restrict__ W_h,
    const float* __restrict__ b_h, const float* __restrict__ W_c,
    const float* __restrict__ b_c, const float* __restrict__ XD,
    const float* __restrict__ Wih_d, const float* __restrict__ Whh_d,
    const unsigned short* __restrict__ EFG, const unsigned short* __restrict__ ENCO,
    const float* __restrict__ mask, float* __restrict__ DECH,
    float* __restrict__ DECC, unsigned short* __restrict__ PRE0,
    unsigned short* __restrict__ ACAT,
    const float* __restrict__ W_out, unsigned short* __restrict__ WOB,
    int do_conv, unsigned* bar) {
  const int bi = blockIdx.x;
  const int tid = threadIdx.x;

  if (bi >= 160) {
    // ---- W_out fp32 -> bf16 converters (64 blocks, no barriers) ----
    if (do_conv) {
      const int cb = bi - 160;
      for (size_t base = (size_t)cb * 2048 + tid * 8;
           base < (size_t)32000 * 1536; base += (size_t)64 * 2048) {
        float4 a = *(const float4*)(W_out + base);
        float4 b = *(const float4*)(W_out + base + 4);
        uint4 o;
        o.x = pack_bf2(a.x, a.y); o.y = pack_bf2(a.z, a.w);
        o.z = pack_bf2(b.x, b.y); o.w = pack_bf2(b.z, b.w);
        *(uint4*)(WOB + base) = o;
      }
    }
    return;
  }

  const bool is_attn = (bi >= 128);
  const int u0 = bi * 4;            // gates blocks only
  unsigned* barB1 = bar;            // arrivals: gates (128/step + 128 init)
  unsigned* barB2 = bar + 256;      // arrivals: attn (32/step)

  __shared__ union {
    struct {
      unsigned short wga[16 * 1544];
      unsigned short xb[32 * 1544];
      float gl[16][33];
    } s;
    struct {
      unsigned short efg[64 * 1160];
      float hcl[1024];
      float scl[64];
      float al[64];
    } a;
    struct { float xl[32][132]; float wi[8][132]; } ini;
  } U;

  const int ob = tid & 31, ouo = (tid >> 5) & 3, ou = u0 + ouo;
  const int w = tid >> 6, lane = tid & 63;
  const int l15 = lane & 15, l4 = lane >> 4;

  if (!is_attn) {
    // ---- init: dec_h = relu([hf,hb]@W_h^T+b_h); dec_c likewise (fp32) ----
    {
      const int mat = bi >> 6, j0i = (bi & 63) * 8;
      const int jj = tid >> 5, b = tid & 31;
      const int sr = tid >> 5, sc = (tid & 31) * 4;
      const float* Wm = mat ? W_c : W_h;
      const float* bias = mat ? b_c : b_h;
      const float* x0 = HFIN + (size_t)(mat ? 2 : 0) * 16384;
      const float* x1 = HFIN + (size_t)(mat ? 3 : 1) * 16384;
      float acc = 0.f;
      for (int kc = 0; kc < 1024; kc += 128) {
#pragma unroll
        for (int i = 0; i < 4; ++i) {
          int r = sr + i * 8;
          const float* src = (kc < 512) ? (x0 + r * 512 + kc + sc)
                                        : (x1 + r * 512 + (kc - 512) + sc);
          *(float4*)&U.ini.xl[r][sc] = *(const float4*)src;
        }
        *(float4*)&U.ini.wi[sr][sc] = *(const float4*)(Wm + (size_t)(j0i + sr) * 1024 + kc + sc);
        __syncthreads();
#pragma unroll
        for (int k = 0; k < 128; k += 4) {
          float4 wv = *(const float4*)&U.ini.wi[jj][k];
          float4 xv = *(const float4*)&U.ini.xl[b][k];
          acc += wv.x * xv.x + wv.y * xv.y + wv.z * xv.z + wv.w * xv.w;
        }
        __syncthreads();
      }
      float v = fmaxf(acc + bias[j0i + jj], 0.f);
      if (mat == 0) {
        st_f32_coh(DECH + b * 512 + j0i + jj, v);
        st_u16_coh(PRE0 + (size_t)b * 1536 + j0i + jj, f2bf(v));
      } else {
        st_f32_coh(DECC + b * 512 + j0i + jj, v);
      }
    }
    arrive8(barB1);
    wait8(barB1, 128);

    // ---- preconvert gates A to bf16 LDS ----
#pragma unroll
    for (int i = 0; i < 24; ++i) {
      int idx = tid + i * 256;
      int r = idx / 384, c4 = idx - (idx / 384) * 384;
      int wrow = (r >> 2) * 512 + u0 + (r & 3);
      int c = c4 * 4;
      float4 v;
      if (c < 512) v = *(const float4*)(Whh_d + (size_t)wrow * 512 + c);
      else         v = *(const float4*)(Wih_d + (size_t)wrow * 1280 + 256 + (c - 512));
      *(uint2*)(U.s.wga + r * 1544 + c) = make_uint2(pack_bf2(v.x, v.y), pack_bf2(v.z, v.w));
    }
    float h_reg = 0.f, c_reg = 0.f;
    if (tid < 128) {
      h_reg = ld_f32_coh(DECH + ob * 512 + ou);
      c_reg = ld_f32_coh(DECC + ob * 512 + ou);
    }

    f4_t cae = {0.f, 0.f, 0.f, 0.f}, cao = {0.f, 0.f, 0.f, 0.f};  // carried

    for (int t = 0; t < 31; ++t) {
      float xg0 = 0, xg1 = 0, xg2 = 0, xg3 = 0;
      if (tid < 128) {
        const float* xp = XD + ((size_t)ob * 31 + t) * 2048 + ou;
        xg0 = xp[0]; xg1 = xp[512]; xg2 = xp[1024]; xg3 = xp[1536];
      }
      if (t == 0) {
        uint4 tmp[24];
#pragma unroll
        for (int i = 0; i < 24; ++i) {
          int idx = tid + i * 256;
          int r = idx / 192, c16 = idx - (idx / 192) * 192;
          asm volatile("global_load_dwordx4 %0, %1, off sc0 sc1"
                       : "=v"(tmp[i]) : "v"(PRE0 + (size_t)r * 1536 + c16 * 8));
        }
        asm volatile("s_waitcnt vmcnt(0)" ::: "memory");
#pragma unroll
        for (int i = 0; i < 24; ++i) {
          int idx = tid + i * 256;
          int r = idx / 192, c16 = idx - (idx / 192) * 192;
          *(uint4*)(U.s.xb + r * 1544 + c16 * 8) = tmp[i];
        }
        __syncthreads();
        if (w < 2) {
          f4_t ae = {0.f, 0.f, 0.f, 0.f}, ao = {0.f, 0.f, 0.f, 0.f};
#pragma unroll
          for (int kk = 0; kk < 48; kk += 2) {
            bfrag_t a0 = *(const bfrag_t*)(U.s.wga + l15 * 1544 + kk * 32 + l4 * 8);
            bfrag_t b0 = *(const bfrag_t*)(U.s.xb + (w * 16 + l15) * 1544 + kk * 32 + l4 * 8);
            bfrag_t a1 = *(const bfrag_t*)(U.s.wga + l15 * 1544 + (kk + 1) * 32 + l4 * 8);
            bfrag_t b1 = *(const bfrag_t*)(U.s.xb + (w * 16 + l15) * 1544 + (kk + 1) * 32 + l4 * 8);
            ae = __builtin_amdgcn_mfma_f32_16x16x32_bf16(a0, b0, ae, 0, 0, 0);
            ao = __builtin_amdgcn_mfma_f32_16x16x32_bf16(a1, b1, ao, 0, 0, 0);
          }
#pragma unroll
          for (int r = 0; r < 4; ++r)
            U.s.gl[l4 * 4 + r][w * 16 + l15] = ae[r] + ao[r];
        }
      } else {
        wait8(barB2, 32u * t);
        uint4 tmp[16];
#pragma unroll
        for (int i = 0; i < 16; ++i) {
          int idx = tid + i * 256;
          int r = idx >> 7, c16 = 64 + (idx & 127);
          asm volatile("global_load_dwordx4 %0, %1, off sc0 sc1"
                       : "=v"(tmp[i]) : "v"(ACAT + ((size_t)r * 31 + (t - 1)) * 1536 + c16 * 8));
        }
        asm volatile("s_waitcnt vmcnt(8)" ::: "memory");
#pragma unroll
        for (int i = 0; i < 8; ++i) {
          int idx = tid + i * 256;
          int r = idx >> 7, c16 = 64 + (idx & 127);
          *(uint4*)(U.s.xb + r * 1544 + c16 * 8) = tmp[i];
        }
        asm volatile("s_waitcnt vmcnt(0)" ::: "memory");
#pragma unroll
        for (int i = 8; i < 16; ++i) {
          int idx = tid + i * 256;
          int r = idx >> 7, c16 = 64 + (idx & 127);
          *(uint4*)(U.s.xb + r * 1544 + c16 * 8) = tmp[i];
        }
        __syncthreads();
        if (w < 2) {
          f4_t ae = cae, ao = cao;
#pragma unroll
          for (int kk = 16; kk < 48; kk += 2) {
            bfrag_t a0 = *(const bfrag_t*)(U.s.wga + l15 * 1544 + kk * 32 + l4 * 8);
            bfrag_t b0 = *(const bfrag_t*)(U.s.xb + (w * 16 + l15) * 1544 + kk * 32 + l4 * 8);
            bfrag_t a1 = *(const bfrag_t*)(U.s.wga + l15 * 1544 + (kk + 1) * 32 + l4 * 8);
            bfrag_t b1 = *(const bfrag_t*)(U.s.xb + (w * 16 + l15) * 1544 + (kk + 1) * 32 + l4 * 8);
            ae = __builtin_amdgcn_mfma_f32_16x16x32_bf16(a0, b0, ae, 0, 0, 0);
            ao = __builtin_amdgcn_mfma_f32_16x16x32_bf16(a1, b1, ao, 0, 0, 0);
          }
#pragma unroll
          for (int r = 0; r < 4; ++r)
            U.s.gl[l4 * 4 + r][w * 16 + l15] = ae[r] + ao[r];
        }
      }
      __syncthreads();
      if (tid < 128) {
        float gi = U.s.gl[ouo][ob] + xg0;
        float gf = U.s.gl[4 + ouo][ob] + xg1;
        float gg = U.s.gl[8 + ouo][ob] + xg2;
        float go = U.s.gl[12 + ouo][ob] + xg3;
        float cn = sigm(gf) * c_reg + sigm(gi) * ftanh(gg);
        float hn = sigm(go) * ftanh(cn);
        h_reg = hn; c_reg = cn;
        st_f32_coh(DECH + ob * 512 + ou, hn);
        st_f32_coh(DECC + ob * 512 + ou, cn);
        st_u16_coh(ACAT + ((size_t)ob * 31 + t) * 1536 + ou, f2bf(hn));
      }
      arrive8(barB1);
      if (t < 30) {
        wait8(barB1, 128u * (t + 2));
        uint4 pre[8];
#pragma unroll
        for (int i = 0; i < 8; ++i) {
          int idx = tid + i * 256;
          int r = idx >> 6, c16 = idx & 63;
          asm volatile("global_load_dwordx4 %0, %1, off sc0 sc1"
                       : "=v"(pre[i]) : "v"(ACAT + ((size_t)r * 31 + t) * 1536 + c16 * 8));
        }
        asm volatile("s_waitcnt vmcnt(0)" ::: "memory");
#pragma unroll
        for (int i = 0; i < 8; ++i) {
          int idx = tid + i * 256;
          int r = idx >> 6, c16 = idx & 63;
          *(uint4*)(U.s.xb + r * 1544 + c16 * 8) = pre[i];
        }
        __syncthreads();
        if (w < 2) {
          f4_t ae = {0.f, 0.f, 0.f, 0.f}, ao = {0.f, 0.f, 0.f, 0.f};
#pragma unroll
          for (int kk = 0; kk < 16; kk += 2) {
            bfrag_t a0 = *(const bfrag_t*)(U.s.wga + l15 * 1544 + kk * 32 + l4 * 8);
            bfrag_t b0 = *(const bfrag_t*)(U.s.xb + (w * 16 + l15) * 1544 + kk * 32 + l4 * 8);
            bfrag_t a1 = *(const bfrag_t*)(U.s.wga + l15 * 1544 + (kk + 1) * 32 + l4 * 8);
            bfrag_t b1 = *(const bfrag_t*)(U.s.xb + (w * 16 + l15) * 1544 + (kk + 1) * 32 + l4 * 8);
            ae = __builtin_amdgcn_mfma_f32_16x16x32_bf16(a0, b0, ae, 0, 0, 0);
            ao = __builtin_amdgcn_mfma_f32_16x16x32_bf16(a1, b1, ao, 0, 0, 0);
          }
          cae = ae; cao = ao;
        }
      }
    }
  } else {
    // ---------------- attention blocks ----------------
    const int b = bi - 128;
    for (int idx = tid; idx < 64 * 144; idx += 256) {
      int s = idx / 144, c16 = idx - (idx / 144) * 144;
      *(uint4*)(U.a.efg + s * 1160 + c16 * 8) =
          *(const uint4*)(EFG + ((size_t)b * 64 + s) * 1152 + c16 * 8);
    }
    for (int t = 0; t < 31; ++t) {
      wait8(barB1, 128u * (t + 2));   // h(t) ready
      {
        int c = tid * 4;
        const float* hp = (c < 512) ? (DECH + b * 512 + c) : (DECC + b * 512 + (c - 512));
        uint4 hv;
        asm volatile("global_load_dwordx4 %0, %1, off sc0 sc1\n\ts_waitcnt vmcnt(0)"
                     : "=v"(hv) : "v"(hp) : "memory");
        *(uint4*)&U.a.hcl[c] = hv;
      }
      __syncthreads();
      {
        const int sidx = tid >> 2, part = tid & 3;
        const unsigned short* eg = U.a.efg + sidx * 1160 + part * 256;
        const float* d = &U.a.hcl[part * 256];
        float acc = 0.f;
#pragma unroll 8
        for (int k = 0; k < 256; k += 8) {
          uint4 v = *(const uint4*)(eg + k);
          acc += bf2f((unsigned short)(v.x & 0xFFFFu)) * d[k + 0];
          acc += bf2f((unsigned short)(v.x >> 16))     * d[k + 1];
          acc += bf2f((unsigned short)(v.y & 0xFFFFu)) * d[k + 2];
          acc += bf2f((unsigned short)(v.y >> 16))     * d[k + 3];
          acc += bf2f((unsigned short)(v.z & 0xFFFFu)) * d[k + 4];
          acc += bf2f((unsigned short)(v.z >> 16))     * d[k + 5];
          acc += bf2f((unsigned short)(v.w & 0xFFFFu)) * d[k + 6];
          acc += bf2f((unsigned short)(v.w >> 16))     * d[k + 7];
        }
        acc += __shfl_xor(acc, 1);
        acc += __shfl_xor(acc, 2);
        if (part == 0)
          U.a.scl[sidx] = acc + bf2f(U.a.efg[sidx * 1160 + 1024]);  // b_df term
      }
      __syncthreads();
      if (tid < 64) {
        float v = U.a.scl[tid];
        float mx = v;
#pragma unroll
        for (int o = 32; o >= 1; o >>= 1) mx = fmaxf(mx, __shfl_xor(mx, o));
        float e = __expf(v - mx) * mask[b * 64 + tid];
        float sm = e;
#pragma unroll
        for (int o = 32; o >= 1; o >>= 1) sm += __shfl_xor(sm, o);
        U.a.al[tid] = e / sm;
      }
      __syncthreads();
      float c0 = 0.f, c1 = 0.f, c2 = 0.f, c3 = 0.f;
#pragma unroll 8
      for (int tp = 0; tp < 64; ++tp) {
        float a = U.a.al[tp];
        const unsigned short* eo = ENCO + ((size_t)b * 64 + tp) * 1024 + tid;
        c0 += a * bf2f(eo[0]);
        c1 += a * bf2f(eo[256]);
        c2 += a * bf2f(eo[512]);
        c3 += a * bf2f(eo[768]);
      }
      unsigned short* ap = ACAT + ((size_t)b * 31 + t) * 1536 + 512;
      st_u16_coh(ap + tid, f2bf(c0));
      st_u16_coh(ap + tid + 256, f2bf(c1));
      st_u16_coh(ap + tid + 512, f2bf(c2));
      st_u16_coh(ap + tid + 768, f2bf(c3));
      arrive8(barB2);
    }
  }
}

// ============================================================================
extern "C" void kernel_launch(void* const* d_in, const int* in_sizes, int n_in,
                              void* d_out, int out_size, void* d_ws, size_t ws_size,
                              hipStream_t stream) {
  const int*   enc_texts = (const int*)  d_in[0];
  const float* enc_mask  = (const float*)d_in[1];
  const int*   dec_texts = (const int*)  d_in[2];
  const float* enc_emb   = (const float*)d_in[3];
  const float* dec_emb   = (const float*)d_in[4];
  const float* Wih_f = (const float*)d_in[5];
  const float* Whh_f = (const float*)d_in[6];
  const float* b_f   = (const float*)d_in[7];
  const float* Wih_b = (const float*)d_in[8];
  const float* Whh_b = (const float*)d_in[9];
  const float* b_b   = (const float*)d_in[10];
  const float* Wih_d = (const float*)d_in[11];
  const float* Whh_d = (const float*)d_in[12];
  const float* b_d   = (const float*)d_in[13];
  const float* W_h   = (const float*)d_in[14];
  const float* b_h   = (const float*)d_in[15];
  const float* W_c   = (const float*)d_in[16];
  const float* b_c   = (const float*)d_in[17];
  const float* W_df  = (const float*)d_in[18];
  const float* b_df  = (const float*)d_in[19];
  const float* W_ef  = (const float*)d_in[20];
  const float* b_ef  = (const float*)d_in[21];
  const float* W_out = (const float*)d_in[22];
  const float* b_out = (const float*)d_in[23];
  float* out = (float*)d_out;

  char* ws = (char*)d_ws;
  size_t off = 0;
  auto alloc = [&](size_t bytes) {
    char* p = ws + off;
    off += (bytes + 255) & ~(size_t)255;
    return p;
  };
  // --- zero-init group ---
  unsigned short* HBF  = (unsigned short*)alloc((size_t)2 * 2 * 16384 * 2);  // [dir][pp][32*512]
  float* DECH = (float*)alloc((size_t)16384 * 4);
  float* DECC = (float*)alloc((size_t)16384 * 4);
  unsigned short* PRE0 = (unsigned short*)alloc((size_t)32 * 1536 * 2);
  unsigned short* ACAT = (unsigned short*)alloc((size_t)1024 * 1536 * 2);
  unsigned* bar = (unsigned*)alloc(4096);  // enc: +0/+256 (uints); dec: via barD
  unsigned* barD = bar + 512;              // dec B1 @ +512, B2 @ +768
  size_t zbytes = off;
  // --- rest ---
  float* XF = (float*)alloc((size_t)2048 * 2048 * 4);
  float* XB = (float*)alloc((size_t)2048 * 2048 * 4);
  float* XD = (float*)alloc((size_t)1024 * 2048 * 4);
  unsigned short* EFb  = (unsigned short*)alloc((size_t)2048 * 1024 * 2);
  unsigned short* ENCO = (unsigned short*)alloc((size_t)2048 * 1024 * 2);
  unsigned short* EMBB = (unsigned short*)alloc((size_t)2048 * 256 * 2);
  unsigned short* DEMB = (unsigned short*)alloc((size_t)1024 * 256 * 2);
  float* HFIN = (float*)alloc((size_t)4 * 16384 * 4);
  // aliases (safe: wdf_t and EFG GEMM run AFTER mega_enc completes)
  unsigned short* EFG = (unsigned short*)XF;  // 2048 x 1152 bf16
  float* WT  = XB;                            // 1152 x 1024 fp32
  // W_out bf16 copy (guarded by ws_size)
  unsigned short* WOB = (unsigned short*)alloc((size_t)32000 * 1536 * 2);
  const bool use16 = (off <= ws_size);

  hipMemsetAsync(d_ws, 0, zbytes, stream);

  gather_enc_kernel<<<2048, 64, 0, stream>>>(enc_texts, enc_emb, EMBB);
  gather_dec_kernel<<<1024, 64, 0, stream>>>(dec_texts, dec_emb, DEMB);

  dim3 blk(256);
  gemm_bt_kernel<<<256, blk, 0, stream>>>(EMBB, 256, Wih_f, 256, 0, b_f, XF, 2048, 2048, 256, 16, 0, 0);
  gemm_bt_kernel<<<256, blk, 0, stream>>>(EMBB, 256, Wih_b, 256, 0, b_b, XB, 2048, 2048, 256, 16, 0, 0);
  gemm_bt_kernel<<<128, blk, 0, stream>>>(DEMB, 256, Wih_d, 1280, 0, b_d, XD, 2048, 1024, 256, 8, 0, 0);

  mega_enc_kernel<<<128, blk, 0, stream>>>(XF, XB, Whh_f, Whh_b, enc_mask, HBF, ENCO, HFIN, bar);

  wdf_t_kernel<<<1025, blk, 0, stream>>>(W_df, b_df, WT);
  gemm_bt_kernel<<<128, blk, 0, stream>>>(ENCO, 1024, W_ef, 1024, 0, b_ef, EFb, 1024, 2048, 1024, 16, 0, 1);
  // EFG = EFb @ WT^T  -> bf16, ldc 1152
  gemm_bt_kernel<<<144, blk, 0, stream>>>(EFb, 1024, WT, 1024, 0, nullptr, EFG, 1152, 2048, 1024, 16, 0, 1);

  // decoder (160 blocks) + folded W_out converters (64 blocks)
  mega_dec_kernel<<<224, blk, 0, stream>>>(HFIN, W_h, b_h, W_c, b_c, XD, Wih_d, Whh_d,
                                           EFG, ENCO, enc_mask, DECH, DECC, PRE0, ACAT,
                                           W_out, WOB, use16 ? 1 : 0, barD);

  // logits = [h, ctx] @ W_out^T + b_out  (97.5 GFLOP, 128x128 swizzled)
  if (use16)
    gemm_bt16_kernel<<<2000, blk, 0, stream>>>(ACAT, 1536, WOB, 1536, b_out, out, 32000, 992, 1536, 8, 1);
  else
    gemm_bt_kernel<<<2000, blk, 0, stream>>>(ACAT, 1536, W_out, 1536, 0, b_out, out, 32000, 992, 1536, 8, 1, 0);
}

// Round 18
// 1141.725 us; speedup vs baseline: 1.1686x; 1.0448x over previous
//
#include <hip/hip_runtime.h>
#include <hip/hip_bf16.h>

// ============================================================================
// seq2seq + attention on MI355X.  B=32, Te=64, Td=32 (31 steps), E=256, H=512,
// V=32000.  Round 18 = round 17 (best: 1193us) + fused independent dispatches:
//   - gather_all: enc+dec gathers in one launch (3072 blocks)
//   - gemm3: XF/XB/XD pre-GEMMs in one launch (640 blocks, same GEMM body)
//   - wdfef: wdf-transpose || EF GEMM in one launch (1153 blocks)
// Megakernels, logits GEMM, conv fold: identical to round 17.
// ============================================================================

typedef __attribute__((ext_vector_type(8))) short bfrag_t;
typedef __attribute__((ext_vector_type(4))) float f4_t;

static __device__ __forceinline__ float bf2f(unsigned short u) {
  union { float f; unsigned int i; } v; v.i = ((unsigned int)u) << 16; return v.f;
}
static __device__ __forceinline__ unsigned short f2bf(float f) {
  union { float f; unsigned int i; } v; v.f = f;
  unsigned int r = v.i + 0x7FFFu + ((v.i >> 16) & 1u);  // RNE
  return (unsigned short)(r >> 16);
}
static __device__ __forceinline__ unsigned int pack_bf2(float lo, float hi) {
  __hip_bfloat162 h2 = __float22bfloat162_rn(make_float2(lo, hi));
  union { __hip_bfloat162 h; unsigned int u; } cv; cv.h = h2;
  return cv.u;
}
static __device__ __forceinline__ float sigm(float x) {
  return __builtin_amdgcn_rcpf(1.f + __expf(-x));
}
static __device__ __forceinline__ float ftanh(float x) {
  float e = __expf(2.f * x);
  return 1.f - 2.f * __builtin_amdgcn_rcpf(e + 1.f);
}

#define GLDS16(g, l)                                                        \
  __builtin_amdgcn_global_load_lds(                                         \
      (const __attribute__((address_space(1))) void*)(g),                   \
      (__attribute__((address_space(3))) void*)(l), 16, 0, 0)

// ---- device-coherent (agent-scope) access helpers: bypass L2 via sc0 sc1 ----
static __device__ __forceinline__ void st_f32_coh(float* p, float v) {
  asm volatile("global_store_dword %0, %1, off sc0 sc1" :: "v"(p), "v"(v) : "memory");
}
static __device__ __forceinline__ void st_u16_coh(unsigned short* p, unsigned short x) {
  asm volatile("global_store_short %0, %1, off sc0 sc1" :: "v"(p), "v"((unsigned)x) : "memory");
}
static __device__ __forceinline__ float ld_f32_coh(const float* p) {
  float v;
  asm volatile("global_load_dword %0, %1, off sc0 sc1\n\ts_waitcnt vmcnt(0)"
               : "=v"(v) : "v"(p) : "memory");
  return v;
}

// ---------------------------------------------------------------------------
// Decoupled fence-free barrier primitives.
// ---------------------------------------------------------------------------
static __device__ __forceinline__ void arrive8(unsigned* base) {
  __syncthreads();
  if (threadIdx.x == 0)
    __hip_atomic_fetch_add(base + (blockIdx.x & 7) * 32, 1u,
                           __ATOMIC_RELAXED, __HIP_MEMORY_SCOPE_AGENT);
}
static __device__ __forceinline__ void wait8(unsigned* base, unsigned target) {
  if (threadIdx.x < 64) {
    unsigned sum;
    do {
      unsigned v = 0;
      if (threadIdx.x < 8)
        v = __hip_atomic_load(base + threadIdx.x * 32,
                              __ATOMIC_RELAXED, __HIP_MEMORY_SCOPE_AGENT);
      v += __shfl_xor(v, 1);
      v += __shfl_xor(v, 2);
      v += __shfl_xor(v, 4);
      sum = __shfl(v, 0);
      if (sum < target) __builtin_amdgcn_s_sleep(2);
    } while (sum < target);
  }
  __syncthreads();
}
static __device__ __forceinline__ void gbar8(unsigned* base, unsigned target) {
  arrive8(base);
  wait8(base, target);
}

// ---------------------------------------------------------------------------
// GEMM body: C = A(bf16, MxK, lda) @ B(fp32 NxldB rows, +bcol0)^T + bias.
// 128x128 tile, BK=32, 4 waves.  id = resolved tile index.
// ---------------------------------------------------------------------------
static __device__ __forceinline__ void gemm_bt_body(
    int id,
    const unsigned short* __restrict__ A, int lda,
    const float* __restrict__ B, int ldb, int bcol0,
    const float* __restrict__ bias, void* __restrict__ Cv, int ldc,
    int Mvalid, int K, int Mt, int obf) {
  __shared__ unsigned short As[128 * 32];
  __shared__ unsigned short Bs[128 * 32];
  const int mb = id % Mt, nb = id / Mt;
  const int m0 = mb * 128, n0 = nb * 128;
  const int tid = threadIdx.x;
  const int w = tid >> 6, lane = tid & 63;
  const int wr = (w >> 1) * 64, wc = (w & 1) * 64;
  const int l15 = lane & 15, l4 = lane >> 4;

  const int arow = w * 16 + (lane >> 2);
  const int acol = (lane & 3) * 8;
  const unsigned short* Ag = A + (size_t)(m0 + arow) * lda + acol;

  const int brow = tid >> 1;
  const int bcol = (tid & 1) * 16;
  const float* Bg = B + (size_t)(n0 + brow) * ldb + bcol0 + bcol;
  unsigned short* Bsw = Bs + brow * 32 + bcol;

  f4_t acc[4][4];
#pragma unroll
  for (int i = 0; i < 4; ++i)
#pragma unroll
    for (int j = 0; j < 4; ++j) {
      acc[i][j].x = 0.f; acc[i][j].y = 0.f; acc[i][j].z = 0.f; acc[i][j].w = 0.f;
    }

  for (int kt = 0; kt < K; kt += 32) {
    GLDS16(Ag + kt, As + w * 512);
    GLDS16(Ag + (size_t)64 * lda + kt, As + (4 + w) * 512);
    float4 q0 = *(const float4*)(Bg + kt);
    float4 q1 = *(const float4*)(Bg + kt + 4);
    float4 q2 = *(const float4*)(Bg + kt + 8);
    float4 q3 = *(const float4*)(Bg + kt + 12);
    union { unsigned int u[8]; uint4 q[2]; } pk;
    pk.u[0] = pack_bf2(q0.x, q0.y); pk.u[1] = pack_bf2(q0.z, q0.w);
    pk.u[2] = pack_bf2(q1.x, q1.y); pk.u[3] = pack_bf2(q1.z, q1.w);
    pk.u[4] = pack_bf2(q2.x, q2.y); pk.u[5] = pack_bf2(q2.z, q2.w);
    pk.u[6] = pack_bf2(q3.x, q3.y); pk.u[7] = pack_bf2(q3.z, q3.w);
    *(uint4*)(Bsw) = pk.q[0];
    *(uint4*)(Bsw + 8) = pk.q[1];
    __syncthreads();
    bfrag_t af[4], bfv[4];
#pragma unroll
    for (int m = 0; m < 4; ++m)
      af[m] = *(const bfrag_t*)(As + (wr + m * 16 + l15) * 32 + l4 * 8);
#pragma unroll
    for (int n = 0; n < 4; ++n)
      bfv[n] = *(const bfrag_t*)(Bs + (wc + n * 16 + l15) * 32 + l4 * 8);
#pragma unroll
    for (int m = 0; m < 4; ++m)
#pragma unroll
      for (int n = 0; n < 4; ++n)
        acc[m][n] = __builtin_amdgcn_mfma_f32_16x16x32_bf16(af[m], bfv[n], acc[m][n], 0, 0, 0);
    __syncthreads();
  }

  const int crb = l4 * 4;
  float* Cf = (float*)Cv;
  unsigned short* Ch = (unsigned short*)Cv;
#pragma unroll
  for (int m = 0; m < 4; ++m)
#pragma unroll
    for (int n = 0; n < 4; ++n)
#pragma unroll
      for (int r = 0; r < 4; ++r) {
        int gr = m0 + wr + m * 16 + crb + r;
        if (gr < Mvalid) {
          int gc = n0 + wc + n * 16 + l15;
          float v = acc[m][n][r] + (bias ? bias[gc] : 0.f);
          if (obf) Ch[(size_t)gr * ldc + gc] = f2bf(v);
          else     Cf[(size_t)gr * ldc + gc] = v;
        }
      }
}

__global__ __launch_bounds__(256) void gemm_bt_kernel(
    const unsigned short* __restrict__ A, int lda,
    const float* __restrict__ B, int ldb, int bcol0,
    const float* __restrict__ bias, void* __restrict__ Cv, int ldc,
    int Mvalid, int K, int Mt, int swz, int obf) {
  int id = blockIdx.x;
  if (swz) { int x = id & 7; id = x * ((int)gridDim.x >> 3) + (id >> 3); }
  gemm_bt_body(id, A, lda, B, ldb, bcol0, bias, Cv, ldc, Mvalid, K, Mt, obf);
}

// Fused XF/XB/XD pre-GEMMs: blocks [0,256) XF, [256,512) XB, [512,640) XD.
__global__ __launch_bounds__(256) void gemm3_kernel(
    const unsigned short* __restrict__ EMBB, const unsigned short* __restrict__ DEMB,
    const float* __restrict__ Wih_f, const float* __restrict__ b_f, float* __restrict__ XF,
    const float* __restrict__ Wih_b, const float* __restrict__ b_b, float* __restrict__ XB,
    const float* __restrict__ Wih_d, const float* __restrict__ b_d, float* __restrict__ XD) {
  const int id = blockIdx.x;
  if (id < 256)
    gemm_bt_body(id, EMBB, 256, Wih_f, 256, 0, b_f, XF, 2048, 2048, 256, 16, 0);
  else if (id < 512)
    gemm_bt_body(id - 256, EMBB, 256, Wih_b, 256, 0, b_b, XB, 2048, 2048, 256, 16, 0);
  else
    gemm_bt_body(id - 512, DEMB, 256, Wih_d, 1280, 0, b_d, XD, 2048, 1024, 256, 8, 0);
}

// Fused wdf-transpose (blocks 0..1024) || EF GEMM (blocks 1025..1152).
__global__ __launch_bounds__(256) void wdfef_kernel(
    const float* __restrict__ W_df, const float* __restrict__ b_df,
    float* __restrict__ WT,
    const unsigned short* __restrict__ ENCO, const float* __restrict__ W_ef,
    const float* __restrict__ b_ef, unsigned short* __restrict__ EFb) {
  const int bid = blockIdx.x;
  if (bid < 1024) {
    __shared__ float tl[32][33];
    const int tx = (bid & 31) * 32, ty = (bid >> 5) * 32;
    const int r = threadIdx.x >> 5, c = threadIdx.x & 31;
#pragma unroll
    for (int i = 0; i < 4; ++i)
      tl[r + i * 8][c] = W_df[(size_t)(ty + r + i * 8) * 1024 + tx + c];
    __syncthreads();
#pragma unroll
    for (int i = 0; i < 4; ++i)
      WT[(size_t)(tx + r + i * 8) * 1024 + ty + c] = tl[c][r + i * 8];
  } else if (bid == 1024) {
    for (int i = threadIdx.x; i < 1024; i += 256)
      WT[(size_t)1024 * 1024 + i] = b_df[i];
  } else {
    gemm_bt_body(bid - 1025, ENCO, 1024, W_ef, 1024, 0, b_ef, EFb, 1024, 2048, 1024, 16, 1);
  }
}

// ---------------------------------------------------------------------------
// bf16 x bf16 variant: C = A @ B^T + bias; both staged via global_load_lds.
// ---------------------------------------------------------------------------
__global__ __launch_bounds__(256) void gemm_bt16_kernel(
    const unsigned short* __restrict__ A, int lda,
    const unsigned short* __restrict__ B, int ldb,
    const float* __restrict__ bias, float* __restrict__ C, int ldc,
    int Mvalid, int K, int Mt, int swz) {
  __shared__ unsigned short As[128 * 32];
  __shared__ unsigned short Bs[128 * 32];
  int id = blockIdx.x;
  if (swz) { int x = id & 7; id = x * ((int)gridDim.x >> 3) + (id >> 3); }
  const int mb = id % Mt, nb = id / Mt;
  const int m0 = mb * 128, n0 = nb * 128;
  const int tid = threadIdx.x;
  const int w = tid >> 6, lane = tid & 63;
  const int wr = (w >> 1) * 64, wc = (w & 1) * 64;
  const int l15 = lane & 15, l4 = lane >> 4;

  const int arow = w * 16 + (lane >> 2);
  const int acol = (lane & 3) * 8;
  const unsigned short* Ag = A + (size_t)(m0 + arow) * lda + acol;
  const unsigned short* Bg = B + (size_t)(n0 + arow) * ldb + acol;

  f4_t acc[4][4];
#pragma unroll
  for (int i = 0; i < 4; ++i)
#pragma unroll
    for (int j = 0; j < 4; ++j) {
      acc[i][j].x = 0.f; acc[i][j].y = 0.f; acc[i][j].z = 0.f; acc[i][j].w = 0.f;
    }

  for (int kt = 0; kt < K; kt += 32) {
    GLDS16(Ag + kt, As + w * 512);
    GLDS16(Ag + (size_t)64 * lda + kt, As + (4 + w) * 512);
    GLDS16(Bg + kt, Bs + w * 512);
    GLDS16(Bg + (size_t)64 * ldb + kt, Bs + (4 + w) * 512);
    __syncthreads();
    bfrag_t af[4], bfv[4];
#pragma unroll
    for (int m = 0; m < 4; ++m)
      af[m] = *(const bfrag_t*)(As + (wr + m * 16 + l15) * 32 + l4 * 8);
#pragma unroll
    for (int n = 0; n < 4; ++n)
      bfv[n] = *(const bfrag_t*)(Bs + (wc + n * 16 + l15) * 32 + l4 * 8);
#pragma unroll
    for (int m = 0; m < 4; ++m)
#pragma unroll
      for (int n = 0; n < 4; ++n)
        acc[m][n] = __builtin_amdgcn_mfma_f32_16x16x32_bf16(af[m], bfv[n], acc[m][n], 0, 0, 0);
    __syncthreads();
  }

  const int crb = l4 * 4;
#pragma unroll
  for (int m = 0; m < 4; ++m)
#pragma unroll
    for (int n = 0; n < 4; ++n)
#pragma unroll
      for (int r = 0; r < 4; ++r) {
        int gr = m0 + wr + m * 16 + crb + r;
        if (gr < Mvalid) {
          int gc = n0 + wc + n * 16 + l15;
          C[(size_t)gr * ldc + gc] = acc[m][n][r] + bias[gc];
        }
      }
}

// ---------------------------------------------------------------------------
// Fused embedding gathers -> bf16 (blocks [0,2048) enc; [2048,3072) dec)
// ---------------------------------------------------------------------------
__global__ void gather_all_kernel(const int* __restrict__ etexts,
                                  const float* __restrict__ etab,
                                  unsigned short* __restrict__ eout,
                                  const int* __restrict__ dtexts,
                                  const float* __restrict__ dtab,
                                  unsigned short* __restrict__ dout) {
  const int bid = blockIdx.x;
  if (bid < 2048) {
    const int row = bid;
    const int tok = etexts[row];
    const float4 v = *(const float4*)(etab + (size_t)tok * 256 + threadIdx.x * 4);
    unsigned short* o = eout + (size_t)row * 256 + threadIdx.x * 4;
    o[0] = f2bf(v.x); o[1] = f2bf(v.y); o[2] = f2bf(v.z); o[3] = f2bf(v.w);
  } else {
    const int row = bid - 2048;
    unsigned short* o = dout + (size_t)row * 256 + threadIdx.x * 4;
    if (row >= 992) { o[0] = 0; o[1] = 0; o[2] = 0; o[3] = 0; return; }
    const int b = row / 31, t2 = row - b * 31;
    const int tok = dtexts[b * 32 + t2];
    const float4 v = *(const float4*)(dtab + (size_t)tok * 256 + threadIdx.x * 4);
    o[0] = f2bf(v.x); o[1] = f2bf(v.y); o[2] = f2bf(v.z); o[3] = f2bf(v.w);
  }
}

// ---------------------------------------------------------------------------
// Encoder megakernel (MFMA).  64 blocks/dir x 8 units.   (round 17 exactly)
// ---------------------------------------------------------------------------
__global__ __launch_bounds__(256) void mega_enc_kernel(
    const float* __restrict__ XF, const float* __restrict__ XB,
    const float* __restrict__ Whh_f, const float* __restrict__ Whh_b,
    const float* __restrict__ mask,
    unsigned short* __restrict__ HBF,   // [dir][pp][32*512] bf16
    unsigned short* __restrict__ ENCO, float* __restrict__ HFIN,
    unsigned* bar) {
  const int bi = blockIdx.x;          // 0..127
  const int dir = bi >> 6;
  const int u0 = (bi & 63) * 8;
  const int tid = threadIdx.x;
  const float* X = dir ? XB : XF;
  const float* W = dir ? Whh_b : Whh_f;
  unsigned short* Hbf = HBF + dir * 32768;
  unsigned* cnt = bar + dir * 256;    // 1 KiB group per direction

  __shared__ unsigned short WA[32 * 520];   // 32 gate-rows: (gate*8+ul)
  __shared__ unsigned short HB[32 * 520];   // row = batch
  __shared__ float Gl[32][33];

  // preload W: row r -> Whh[(r>>3)*512 + u0 + (r&7)]
#pragma unroll
  for (int i = 0; i < 16; ++i) {
    int idx = tid + i * 256;
    int r = idx >> 7, c4 = idx & 127;
    const float4 v = *(const float4*)(W + (size_t)((r >> 3) * 512 + u0 + (r & 7)) * 512 + c4 * 4);
    *(uint2*)(WA + r * 520 + c4 * 4) = make_uint2(pack_bf2(v.x, v.y), pack_bf2(v.z, v.w));
  }
  __syncthreads();

  const int w = tid >> 6, lane = tid & 63;
  const int l15 = lane & 15, l4 = lane >> 4;
  const int wrow = (w >> 1) * 16, wcol = (w & 1) * 16;   // wave tile base

  bfrag_t afr[16];
#pragma unroll
  for (int kk = 0; kk < 16; ++kk)
    afr[kk] = *(const bfrag_t*)(WA + (wrow + l15) * 520 + kk * 32 + l4 * 8);

  const int ob = tid & 31, ouo = tid >> 5;   // batch, unit offset (0..7)
  const int ou = u0 + ouo;
  float h_reg = 0.f, c_reg = 0.f;

  unsigned tgt = 0;
  for (int s = 0; s < 64; ++s) {
    const int t = dir ? (63 - s) : s;
    const int pp = s & 1;
    const float* xp = X + ((size_t)ob * 64 + t) * 2048 + ou;
    float xg0 = xp[0], xg1 = xp[512], xg2 = xp[1024], xg3 = xp[1536];
    float mval = mask[ob * 64 + t];
    // stage h (bf16, 32 rows x 64 uint4/row) via coherent loads
    const unsigned short* hsrc = Hbf + pp * 16384;
    uint4 tmp[8];
#pragma unroll
    for (int i = 0; i < 8; ++i) {
      int idx = tid + i * 256;
      int r = idx >> 6, c = idx & 63;
      asm volatile("global_load_dwordx4 %0, %1, off sc0 sc1"
                   : "=v"(tmp[i]) : "v"(hsrc + r * 512 + c * 8));
    }
    asm volatile("s_waitcnt vmcnt(0)" ::: "memory");
#pragma unroll
    for (int i = 0; i < 8; ++i) {
      int idx = tid + i * 256;
      int r = idx >> 6, c = idx & 63;
      *(uint4*)(HB + r * 520 + c * 8) = tmp[i];
    }
    __syncthreads();
    {
      f4_t ae = {0.f, 0.f, 0.f, 0.f}, ao = {0.f, 0.f, 0.f, 0.f};
#pragma unroll
      for (int kk = 0; kk < 16; kk += 2) {
        bfrag_t b0 = *(const bfrag_t*)(HB + (wcol + l15) * 520 + kk * 32 + l4 * 8);
        bfrag_t b1 = *(const bfrag_t*)(HB + (wcol + l15) * 520 + (kk + 1) * 32 + l4 * 8);
        ae = __builtin_amdgcn_mfma_f32_16x16x32_bf16(afr[kk], b0, ae, 0, 0, 0);
        ao = __builtin_amdgcn_mfma_f32_16x16x32_bf16(afr[kk + 1], b1, ao, 0, 0, 0);
      }
#pragma unroll
      for (int r = 0; r < 4; ++r)
        Gl[wrow + l4 * 4 + r][wcol + l15] = ae[r] + ao[r];
    }
    __syncthreads();
    {
      float gi = Gl[ouo][ob] + xg0;
      float gf = Gl[8 + ouo][ob] + xg1;
      float gg = Gl[16 + ouo][ob] + xg2;
      float go = Gl[24 + ouo][ob] + xg3;
      float cn = sigm(gf) * c_reg + sigm(gi) * ftanh(gg);
      float hn = sigm(go) * ftanh(cn);
      float hmix = mval * hn + (1.f - mval) * h_reg;
      float cmix = mval * cn + (1.f - mval) * c_reg;
      h_reg = hmix; c_reg = cmix;
      ENCO[((size_t)ob * 64 + t) * 1024 + dir * 512 + ou] = f2bf(hmix * mval);
      st_u16_coh(Hbf + (pp ^ 1) * 16384 + ob * 512 + ou, f2bf(hmix));
      if (s == 63) {
        HFIN[dir * 16384 + ob * 512 + ou] = hmix;
        HFIN[(2 + dir) * 16384 + ob * 512 + ou] = cmix;
      }
    }
    if (s < 63) { tgt += 64; gbar8(cnt, tgt); }
  }
}

// ---------------------------------------------------------------------------
// Decoder megakernel (MFMA) + folded W_out->bf16 converters.  (round 17)
// Grid 224: 0-127 gates, 128-159 attention, 160-223 converters.
// ---------------------------------------------------------------------------
__global__ __launch_bounds__(256) void mega_dec_kernel(
    const float* __restrict__ HFIN, const float* __restrict__ W_h,
    const float* __restrict__ b_h, const float* __restrict__ W_c,
    const float* __restrict__ b_c, const float* __restrict__ XD,
    const float* __restrict__ Wih_d, const float* __restrict__ Whh_d,
    const unsigned short* __restrict__ EFG, const unsigned short* __restrict__ ENCO,
    const float* __restrict__ mask, float* __restrict__ DECH,
    float* __restrict__ DECC, unsigned short* __restrict__ PRE0,
    unsigned short* __restrict__ ACAT,
    const float* __restrict__ W_out, unsigned short* __restrict__ WOB,
    int do_conv, unsigned* bar) {
  const int bi = blockIdx.x;
  const int tid = threadIdx.x;

  if (bi >= 160) {
    // ---- W_out fp32 -> bf16 converters (64 blocks, no barriers) ----
    if (do_conv) {
      const int cb = bi - 160;
      for (size_t base = (size_t)cb * 2048 + tid * 8;
           base < (size_t)32000 * 1536; base += (size_t)64 * 2048) {
        float4 a = *(const float4*)(W_out + base);
        float4 b = *(const float4*)(W_out + base + 4);
        uint4 o;
        o.x = pack_bf2(a.x, a.y); o.y = pack_bf2(a.z, a.w);
        o.z = pack_bf2(b.x, b.y); o.w = pack_bf2(b.z, b.w);
        *(uint4*)(WOB + base) = o;
      }
    }
    return;
  }

  const bool is_attn = (bi >= 128);
  const int u0 = bi * 4;            // gates blocks only
  unsigned* barB1 = bar;            // arrivals: gates (128/step + 128 init)
  unsigned* barB2 = bar + 256;      // arrivals: attn (32/step)

  __shared__ union {
    struct {
      unsigned short wga[16 * 1544];
      unsigned short xb[32 * 1544];
      float gl[16][33];
    } s;
    struct {
      unsigned short efg[64 * 1160];
      float hcl[1024];
      float scl[64];
      float al[64];
    } a;
    struct { float xl[32][132]; float wi[8][132]; } ini;
  } U;

  const int ob = tid & 31, ouo = (tid >> 5) & 3, ou = u0 + ouo;
  const int w = tid >> 6, lane = tid & 63;
  const int l15 = lane & 15, l4 = lane >> 4;

  if (!is_attn) {
    // ---- init: dec_h = relu([hf,hb]@W_h^T+b_h); dec_c likewise (fp32) ----
    {
      const int mat = bi >> 6, j0i = (bi & 63) * 8;
      const int jj = tid >> 5, b = tid & 31;
      const int sr = tid >> 5, sc = (tid & 31) * 4;
      const float* Wm = mat ? W_c : W_h;
      const float* bias = mat ? b_c : b_h;
      const float* x0 = HFIN + (size_t)(mat ? 2 : 0) * 16384;
      const float* x1 = HFIN + (size_t)(mat ? 3 : 1) * 16384;
      float acc = 0.f;
      for (int kc = 0; kc < 1024; kc += 128) {
#pragma unroll
        for (int i = 0; i < 4; ++i) {
          int r = sr + i * 8;
          const float* src = (kc < 512) ? (x0 + r * 512 + kc + sc)
                                        : (x1 + r * 512 + (kc - 512) + sc);
          *(float4*)&U.ini.xl[r][sc] = *(const float4*)src;
        }
        *(float4*)&U.ini.wi[sr][sc] = *(const float4*)(Wm + (size_t)(j0i + sr) * 1024 + kc + sc);
        __syncthreads();
#pragma unroll
        for (int k = 0; k < 128; k += 4) {
          float4 wv = *(const float4*)&U.ini.wi[jj][k];
          float4 xv = *(const float4*)&U.ini.xl[b][k];
          acc += wv.x * xv.x + wv.y * xv.y + wv.z * xv.z + wv.w * xv.w;
        }
        __syncthreads();
      }
      float v = fmaxf(acc + bias[j0i + jj], 0.f);
      if (mat == 0) {
        st_f32_coh(DECH + b * 512 + j0i + jj, v);
        st_u16_coh(PRE0 + (size_t)b * 1536 + j0i + jj, f2bf(v));
      } else {
        st_f32_coh(DECC + b * 512 + j0i + jj, v);
      }
    }
    arrive8(barB1);
    wait8(barB1, 128);

    // ---- preconvert gates A to bf16 LDS ----
#pragma unroll
    for (int i = 0; i < 24; ++i) {
      int idx = tid + i * 256;
      int r = idx / 384, c4 = idx - (idx / 384) * 384;
      int wrow = (r >> 2) * 512 + u0 + (r & 3);
      int c = c4 * 4;
      float4 v;
      if (c < 512) v = *(const float4*)(Whh_d + (size_t)wrow * 512 + c);
      else         v = *(const float4*)(Wih_d + (size_t)wrow * 1280 + 256 + (c - 512));
      *(uint2*)(U.s.wga + r * 1544 + c) = make_uint2(pack_bf2(v.x, v.y), pack_bf2(v.z, v.w));
    }
    float h_reg = 0.f, c_reg = 0.f;
    if (tid < 128) {
      h_reg = ld_f32_coh(DECH + ob * 512 + ou);
      c_reg = ld_f32_coh(DECC + ob * 512 + ou);
    }

    f4_t cae = {0.f, 0.f, 0.f, 0.f}, cao = {0.f, 0.f, 0.f, 0.f};  // carried

    for (int t = 0; t < 31; ++t) {
      float xg0 = 0, xg1 = 0, xg2 = 0, xg3 = 0;
      if (tid < 128) {
        const float* xp = XD + ((size_t)ob * 31 + t) * 2048 + ou;
        xg0 = xp[0]; xg1 = xp[512]; xg2 = xp[1024]; xg3 = xp[1536];
      }
      if (t == 0) {
        uint4 tmp[24];
#pragma unroll
        for (int i = 0; i < 24; ++i) {
          int idx = tid + i * 256;
          int r = idx / 192, c16 = idx - (idx / 192) * 192;
          asm volatile("global_load_dwordx4 %0, %1, off sc0 sc1"
                       : "=v"(tmp[i]) : "v"(PRE0 + (size_t)r * 1536 + c16 * 8));
        }
        asm volatile("s_waitcnt vmcnt(0)" ::: "memory");
#pragma unroll
        for (int i = 0; i < 24; ++i) {
          int idx = tid + i * 256;
          int r = idx / 192, c16 = idx - (idx / 192) * 192;
          *(uint4*)(U.s.xb + r * 1544 + c16 * 8) = tmp[i];
        }
        __syncthreads();
        if (w < 2) {
          f4_t ae = {0.f, 0.f, 0.f, 0.f}, ao = {0.f, 0.f, 0.f, 0.f};
#pragma unroll
          for (int kk = 0; kk < 48; kk += 2) {
            bfrag_t a0 = *(const bfrag_t*)(U.s.wga + l15 * 1544 + kk * 32 + l4 * 8);
            bfrag_t b0 = *(const bfrag_t*)(U.s.xb + (w * 16 + l15) * 1544 + kk * 32 + l4 * 8);
            bfrag_t a1 = *(const bfrag_t*)(U.s.wga + l15 * 1544 + (kk + 1) * 32 + l4 * 8);
            bfrag_t b1 = *(const bfrag_t*)(U.s.xb + (w * 16 + l15) * 1544 + (kk + 1) * 32 + l4 * 8);
            ae = __builtin_amdgcn_mfma_f32_16x16x32_bf16(a0, b0, ae, 0, 0, 0);
            ao = __builtin_amdgcn_mfma_f32_16x16x32_bf16(a1, b1, ao, 0, 0, 0);
          }
#pragma unroll
          for (int r = 0; r < 4; ++r)
            U.s.gl[l4 * 4 + r][w * 16 + l15] = ae[r] + ao[r];
        }
      } else {
        wait8(barB2, 32u * t);
        uint4 tmp[16];
#pragma unroll
        for (int i = 0; i < 16; ++i) {
          int idx = tid + i * 256;
          int r = idx >> 7, c16 = 64 + (idx & 127);
          asm volatile("global_load_dwordx4 %0, %1, off sc0 sc1"
                       : "=v"(tmp[i]) : "v"(ACAT + ((size_t)r * 31 + (t - 1)) * 1536 + c16 * 8));
        }
        asm volatile("s_waitcnt vmcnt(8)" ::: "memory");
#pragma unroll
        for (int i = 0; i < 8; ++i) {
          int idx = tid + i * 256;
          int r = idx >> 7, c16 = 64 + (idx & 127);
          *(uint4*)(U.s.xb + r * 1544 + c16 * 8) = tmp[i];
        }
        asm volatile("s_waitcnt vmcnt(0)" ::: "memory");
#pragma unroll
        for (int i = 8; i < 16; ++i) {
          int idx = tid + i * 256;
          int r = idx >> 7, c16 = 64 + (idx & 127);
          *(uint4*)(U.s.xb + r * 1544 + c16 * 8) = tmp[i];
        }
        __syncthreads();
        if (w < 2) {
          f4_t ae = cae, ao = cao;
#pragma unroll
          for (int kk = 16; kk < 48; kk += 2) {
            bfrag_t a0 = *(const bfrag_t*)(U.s.wga + l15 * 1544 + kk * 32 + l4 * 8);
            bfrag_t b0 = *(const bfrag_t*)(U.s.xb + (w * 16 + l15) * 1544 + kk * 32 + l4 * 8);
            bfrag_t a1 = *(const bfrag_t*)(U.s.wga + l15 * 1544 + (kk + 1) * 32 + l4 * 8);
            bfrag_t b1 = *(const bfrag_t*)(U.s.xb + (w * 16 + l15) * 1544 + (kk + 1) * 32 + l4 * 8);
            ae = __builtin_amdgcn_mfma_f32_16x16x32_bf16(a0, b0, ae, 0, 0, 0);
            ao = __builtin_amdgcn_mfma_f32_16x16x32_bf16(a1, b1, ao, 0, 0, 0);
          }
#pragma unroll
          for (int r = 0; r < 4; ++r)
            U.s.gl[l4 * 4 + r][w * 16 + l15] = ae[r] + ao[r];
        }
      }
      __syncthreads();
      if (tid < 128) {
        float gi = U.s.gl[ouo][ob] + xg0;
        float gf = U.s.gl[4 + ouo][ob] + xg1;
        float gg = U.s.gl[8 + ouo][ob] + xg2;
        float go = U.s.gl[12 + ouo][ob] + xg3;
        float cn = sigm(gf) * c_reg + sigm(gi) * ftanh(gg);
        float hn = sigm(go) * ftanh(cn);
        h_reg = hn; c_reg = cn;
        st_f32_coh(DECH + ob * 512 + ou, hn);
        st_f32_coh(DECC + ob * 512 + ou, cn);
        st_u16_coh(ACAT + ((size_t)ob * 31 + t) * 1536 + ou, f2bf(hn));
      }
      arrive8(barB1);
      if (t < 30) {
        wait8(barB1, 128u * (t + 2));
        uint4 pre[8];
#pragma unroll
        for (int i = 0; i < 8; ++i) {
          int idx = tid + i * 256;
          int r = idx >> 6, c16 = idx & 63;
          asm volatile("global_load_dwordx4 %0, %1, off sc0 sc1"
                       : "=v"(pre[i]) : "v"(ACAT + ((size_t)r * 31 + t) * 1536 + c16 * 8));
        }
        asm volatile("s_waitcnt vmcnt(0)" ::: "memory");
#pragma unroll
        for (int i = 0; i < 8; ++i) {
          int idx = tid + i * 256;
          int r = idx >> 6, c16 = idx & 63;
          *(uint4*)(U.s.xb + r * 1544 + c16 * 8) = pre[i];
        }
        __syncthreads();
        if (w < 2) {
          f4_t ae = {0.f, 0.f, 0.f, 0.f}, ao = {0.f, 0.f, 0.f, 0.f};
#pragma unroll
          for (int kk = 0; kk < 16; kk += 2) {
            bfrag_t a0 = *(const bfrag_t*)(U.s.wga + l15 * 1544 + kk * 32 + l4 * 8);
            bfrag_t b0 = *(const bfrag_t*)(U.s.xb + (w * 16 + l15) * 1544 + kk * 32 + l4 * 8);
            bfrag_t a1 = *(const bfrag_t*)(U.s.wga + l15 * 1544 + (kk + 1) * 32 + l4 * 8);
            bfrag_t b1 = *(const bfrag_t*)(U.s.xb + (w * 16 + l15) * 1544 + (kk + 1) * 32 + l4 * 8);
            ae = __builtin_amdgcn_mfma_f32_16x16x32_bf16(a0, b0, ae, 0, 0, 0);
            ao = __builtin_amdgcn_mfma_f32_16x16x32_bf16(a1, b1, ao, 0, 0, 0);
          }
          cae = ae; cao = ao;
        }
      }
    }
  } else {
    // ---------------- attention blocks ----------------
    const int b = bi - 128;
    for (int idx = tid; idx < 64 * 144; idx += 256) {
      int s = idx / 144, c16 = idx - (idx / 144) * 144;
      *(uint4*)(U.a.efg + s * 1160 + c16 * 8) =
          *(const uint4*)(EFG + ((size_t)b * 64 + s) * 1152 + c16 * 8);
    }
    for (int t = 0; t < 31; ++t) {
      wait8(barB1, 128u * (t + 2));   // h(t) ready
      {
        int c = tid * 4;
        const float* hp = (c < 512) ? (DECH + b * 512 + c) : (DECC + b * 512 + (c - 512));
        uint4 hv;
        asm volatile("global_load_dwordx4 %0, %1, off sc0 sc1\n\ts_waitcnt vmcnt(0)"
                     : "=v"(hv) : "v"(hp) : "memory");
        *(uint4*)&U.a.hcl[c] = hv;
      }
      __syncthreads();
      {
        const int sidx = tid >> 2, part = tid & 3;
        const unsigned short* eg = U.a.efg + sidx * 1160 + part * 256;
        const float* d = &U.a.hcl[part * 256];
        float acc = 0.f;
#pragma unroll 8
        for (int k = 0; k < 256; k += 8) {
          uint4 v = *(const uint4*)(eg + k);
          acc += bf2f((unsigned short)(v.x & 0xFFFFu)) * d[k + 0];
          acc += bf2f((unsigned short)(v.x >> 16))     * d[k + 1];
          acc += bf2f((unsigned short)(v.y & 0xFFFFu)) * d[k + 2];
          acc += bf2f((unsigned short)(v.y >> 16))     * d[k + 3];
          acc += bf2f((unsigned short)(v.z & 0xFFFFu)) * d[k + 4];
          acc += bf2f((unsigned short)(v.z >> 16))     * d[k + 5];
          acc += bf2f((unsigned short)(v.w & 0xFFFFu)) * d[k + 6];
          acc += bf2f((unsigned short)(v.w >> 16))     * d[k + 7];
        }
        acc += __shfl_xor(acc, 1);
        acc += __shfl_xor(acc, 2);
        if (part == 0)
          U.a.scl[sidx] = acc + bf2f(U.a.efg[sidx * 1160 + 1024]);  // b_df term
      }
      __syncthreads();
      if (tid < 64) {
        float v = U.a.scl[tid];
        float mx = v;
#pragma unroll
        for (int o = 32; o >= 1; o >>= 1) mx = fmaxf(mx, __shfl_xor(mx, o));
        float e = __expf(v - mx) * mask[b * 64 + tid];
        float sm = e;
#pragma unroll
        for (int o = 32; o >= 1; o >>= 1) sm += __shfl_xor(sm, o);
        U.a.al[tid] = e / sm;
      }
      __syncthreads();
      float c0 = 0.f, c1 = 0.f, c2 = 0.f, c3 = 0.f;
#pragma unroll 8
      for (int tp = 0; tp < 64; ++tp) {
        float a = U.a.al[tp];
        const unsigned short* eo = ENCO + ((size_t)b * 64 + tp) * 1024 + tid;
        c0 += a * bf2f(eo[0]);
        c1 += a * bf2f(eo[256]);
        c2 += a * bf2f(eo[512]);
        c3 += a * bf2f(eo[768]);
      }
      unsigned short* ap = ACAT + ((size_t)b * 31 + t) * 1536 + 512;
      st_u16_coh(ap + tid, f2bf(c0));
      st_u16_coh(ap + tid + 256, f2bf(c1));
      st_u16_coh(ap + tid + 512, f2bf(c2));
      st_u16_coh(ap + tid + 768, f2bf(c3));
      arrive8(barB2);
    }
  }
}

// ============================================================================
extern "C" void kernel_launch(void* const* d_in, const int* in_sizes, int n_in,
                              void* d_out, int out_size, void* d_ws, size_t ws_size,
                              hipStream_t stream) {
  const int*   enc_texts = (const int*)  d_in[0];
  const float* enc_mask  = (const float*)d_in[1];
  const int*   dec_texts = (const int*)  d_in[2];
  const float* enc_emb   = (const float*)d_in[3];
  const float* dec_emb   = (const float*)d_in[4];
  const float* Wih_f = (const float*)d_in[5];
  const float* Whh_f = (const float*)d_in[6];
  const float* b_f   = (const float*)d_in[7];
  const float* Wih_b = (const float*)d_in[8];
  const float* Whh_b = (const float*)d_in[9];
  const float* b_b   = (const float*)d_in[10];
  const float* Wih_d = (const float*)d_in[11];
  const float* Whh_d = (const float*)d_in[12];
  const float* b_d   = (const float*)d_in[13];
  const float* W_h   = (const float*)d_in[14];
  const float* b_h   = (const float*)d_in[15];
  const float* W_c   = (const float*)d_in[16];
  const float* b_c   = (const float*)d_in[17];
  const float* W_df  = (const float*)d_in[18];
  const float* b_df  = (const float*)d_in[19];
  const float* W_ef  = (const float*)d_in[20];
  const float* b_ef  = (const float*)d_in[21];
  const float* W_out = (const float*)d_in[22];
  const float* b_out = (const float*)d_in[23];
  float* out = (float*)d_out;

  char* ws = (char*)d_ws;
  size_t off = 0;
  auto alloc = [&](size_t bytes) {
    char* p = ws + off;
    off += (bytes + 255) & ~(size_t)255;
    return p;
  };
  // --- zero-init group ---
  unsigned short* HBF  = (unsigned short*)alloc((size_t)2 * 2 * 16384 * 2);  // [dir][pp][32*512]
  float* DECH = (float*)alloc((size_t)16384 * 4);
  float* DECC = (float*)alloc((size_t)16384 * 4);
  unsigned short* PRE0 = (unsigned short*)alloc((size_t)32 * 1536 * 2);
  unsigned short* ACAT = (unsigned short*)alloc((size_t)1024 * 1536 * 2);
  unsigned* bar = (unsigned*)alloc(4096);  // enc: +0/+256 (uints); dec: via barD
  unsigned* barD = bar + 512;              // dec B1 @ +512, B2 @ +768
  size_t zbytes = off;
  // --- rest ---
  float* XF = (float*)alloc((size_t)2048 * 2048 * 4);
  float* XB = (float*)alloc((size_t)2048 * 2048 * 4);
  float* XD = (float*)alloc((size_t)1024 * 2048 * 4);
  unsigned short* EFb  = (unsigned short*)alloc((size_t)2048 * 1024 * 2);
  unsigned short* ENCO = (unsigned short*)alloc((size_t)2048 * 1024 * 2);
  unsigned short* EMBB = (unsigned short*)alloc((size_t)2048 * 256 * 2);
  unsigned short* DEMB = (unsigned short*)alloc((size_t)1024 * 256 * 2);
  float* HFIN = (float*)alloc((size_t)4 * 16384 * 4);
  // aliases (safe: wdfef and EFG GEMM run AFTER mega_enc completes)
  unsigned short* EFG = (unsigned short*)XF;  // 2048 x 1152 bf16
  float* WT  = XB;                            // 1152 x 1024 fp32
  // W_out bf16 copy (guarded by ws_size)
  unsigned short* WOB = (unsigned short*)alloc((size_t)32000 * 1536 * 2);
  const bool use16 = (off <= ws_size);

  hipMemsetAsync(d_ws, 0, zbytes, stream);

  dim3 blk(256);
  gather_all_kernel<<<3072, 64, 0, stream>>>(enc_texts, enc_emb, EMBB,
                                             dec_texts, dec_emb, DEMB);

  // fused XF/XB/XD pre-GEMMs (640 blocks)
  gemm3_kernel<<<640, blk, 0, stream>>>(EMBB, DEMB,
                                        Wih_f, b_f, XF,
                                        Wih_b, b_b, XB,
                                        Wih_d, b_d, XD);

  mega_enc_kernel<<<128, blk, 0, stream>>>(XF, XB, Whh_f, Whh_b, enc_mask, HBF, ENCO, HFIN, bar);

  // fused wdf transpose || EF GEMM (1153 blocks)
  wdfef_kernel<<<1153, blk, 0, stream>>>(W_df, b_df, WT, ENCO, W_ef, b_ef, EFb);
  // EFG = EFb @ WT^T  -> bf16, ldc 1152
  gemm_bt_kernel<<<144, blk, 0, stream>>>(EFb, 1024, WT, 1024, 0, nullptr, EFG, 1152, 2048, 1024, 16, 0, 1);

  // decoder (160 blocks) + folded W_out converters (64 blocks)
  mega_dec_kernel<<<224, blk, 0, stream>>>(HFIN, W_h, b_h, W_c, b_c, XD, Wih_d, Whh_d,
                                           EFG, ENCO, enc_mask, DECH, DECC, PRE0, ACAT,
                                           W_out, WOB, use16 ? 1 : 0, barD);

  // logits = [h, ctx] @ W_out^T + b_out  (97.5 GFLOP, 128x128 swizzled)
  if (use16)
    gemm_bt16_kernel<<<2000, blk, 0, stream>>>(ACAT, 1536, WOB, 1536, b_out, out, 32000, 992, 1536, 8, 1);
  else
    gemm_bt_kernel<<<2000, blk, 0, stream>>>(ACAT, 1536, W_out, 1536, 0, b_out, out, 32000, 992, 1536, 8, 1, 0);
}